// Round 7
// baseline (1008.654 us; speedup 1.0000x reference)
//
#include <hip/hip_runtime.h>
#include <hip/hip_bf16.h>

typedef __attribute__((ext_vector_type(8))) short bf16x8;
typedef __attribute__((ext_vector_type(4))) float f32x4;

static inline int cdiv(int a, int b) { return (a + b - 1) / b; }

__device__ __forceinline__ ushort f2bf(float f) {
    unsigned u = __float_as_uint(f);
    unsigned r = (u + 0x7FFFu + ((u >> 16) & 1u)) >> 16;
    return (ushort)r;
}
__device__ __forceinline__ unsigned pack2bf(float lo, float hi) {
    unsigned r;
    asm("v_cvt_pk_bf16_f32 %0, %1, %2" : "=v"(r) : "v"(lo), "v"(hi));
    return r;
}
__device__ __forceinline__ float bf2f(ushort u) {
    return __uint_as_float((unsigned)u << 16);
}

// ---------------------------------------------------------------------------
// Weight repack: w[co][ci][t] (fp32) -> wt[t][co_pad][ci_pad] (bf16), zero-pad.
// ---------------------------------------------------------------------------
__global__ __launch_bounds__(256)
void transpose_w(const float* __restrict__ w, ushort* __restrict__ wt,
                 int Cout, int CoutPad, int Cin, int Cin_pad, int KK, int total) {
    int idx = blockIdx.x * 256 + threadIdx.x;
    if (idx >= total) return;
    int ci = idx % Cin_pad;
    int rem = idx / Cin_pad;
    int co = rem % CoutPad;
    int t  = rem / CoutPad;
    float v = (ci < Cin && co < Cout) ? w[((size_t)co * Cin + ci) * KK + t] : 0.f;
    wt[idx] = f2bf(v);
}

// ---------------------------------------------------------------------------
// ConvTranspose weight repack: torch wt[ci][co][ky][kx] -> wtp[t][co][ci_pad]
// ---------------------------------------------------------------------------
__device__ const int g_tky[9] = {1, 1, 1, 0, 2, 0, 0, 2, 2};
__device__ const int g_tkx[9] = {1, 0, 2, 1, 1, 0, 2, 0, 2};

__global__ __launch_bounds__(256)
void transpose_wt(const float* __restrict__ wt, ushort* __restrict__ dst,
                  int Cin, int Cout, int Cin_pad, int total) {
    int idx = blockIdx.x * 256 + threadIdx.x;
    if (idx >= total) return;
    int ci = idx % Cin_pad;
    int rem = idx / Cin_pad;
    int co = rem % Cout;
    int t  = rem / Cout;
    float v = 0.f;
    if (ci < Cin)
        v = wt[((size_t)(ci * Cout + co) * 3 + g_tky[t]) * 3 + g_tkx[t]];
    dst[idx] = f2bf(v);
}

// ---------------------------------------------------------------------------
// Implicit-GEMM conv via MFMA 16x16x32 bf16, v4 (occupancy-first).
//  - cp-fastest staging: LDS write banks 2-way (free); global coalesces via
//    same-line merging across lanes {cp, cp+16, cp+32, cp+48}.
//  - in1 fp32 (packed v_cvt_pk_bf16_f32), in2 bf16 (upsampled map).
//  - OUTMODE: 0 = plain fp32, 1 = atomic fp32 (split-K), 2 = plain bf16.
//  - No residual fusion (costs VGPR -> occupancy; R6 post-mortem).
// ---------------------------------------------------------------------------
template<int K, int TY, int TX, int NSPLIT, int MSPLIT, int MT, bool VEC4, int OUTMODE>
__global__ __launch_bounds__(256)
void conv_mfma4(const float* __restrict__ in1, int C1,
                const ushort* __restrict__ in2, int C2, int Cin,
                const ushort* __restrict__ wt,
                void* __restrict__ outDst,
                int H, int W, int Cout, int CoutPad, int Cin_pad,
                int tilesX, int nchunks, int cps) {
    constexpr int P = K / 2;
    constexpr int XOFF = (K == 1) ? 0 : 4;
    constexpr int JOFF = XOFF - P;
    constexpr int HXs = (TX + K - 1 + JOFF + 3) & ~3;
    constexpr int HY = TY + K - 1;
    constexpr int PITCH = 40;
    constexpr int KK = K * K;
    constexpr int PXW = TY * TX / NSPLIT;
    constexpr int NT = PXW / 16;
    constexpr int G = HXs / 4;
    constexpr int NITEM = 16 * HY * G;

    __shared__ ushort sT[HY * HXs * PITCH];

    const int tid = threadIdx.x;
    const int lane = tid & 63, wv = tid >> 6;
    const int nwave = wv % NSPLIT, mwave = wv / NSPLIT;
    const int l15 = lane & 15, lg = lane >> 4;

    const int txi = blockIdx.x % tilesX;
    const int tyi = blockIdx.x / tilesX;
    const int b = blockIdx.z;
    const int x0 = txi * TX, y0 = tyi * TY;
    const size_t HW = (size_t)H * W;

    const int co0 = mwave * (MT * 16);

    int posBase[NT], py_[NT], px_[NT];
    #pragma unroll
    for (int nt = 0; nt < NT; ++nt) {
        int pidx = nwave * PXW + nt * 16 + l15;
        int py = pidx / TX, px = pidx % TX;
        py_[nt] = py; px_[nt] = px;
        posBase[nt] = (py * HXs + px + JOFF) * PITCH + lg * 8;
    }
    const int aoff = l15 * Cin_pad + lg * 8;

    f32x4 acc[MT][NT];
    #pragma unroll
    for (int i = 0; i < MT; ++i)
        #pragma unroll
        for (int j = 0; j < NT; ++j) acc[i][j] = (f32x4)0.f;

    const int c0 = blockIdx.y * cps;
    const int c1 = (c0 + cps < nchunks) ? c0 + cps : nchunks;

    for (int c = c0; c < c1; ++c) {
        const int ci0 = c * 32;
        __syncthreads();
        // ---- stage halo tile, cp-fastest (bank-conflict-free) ----
        for (int i = tid; i < NITEM; i += 256) {
            int cp = i & 15;
            int g  = (i >> 4) % G;
            int rr = i / (16 * G);
            int ci = ci0 + cp * 2;
            int y = y0 - P + rr;
            int xg = x0 - XOFF + g * 4;
            ushort* dp = &sT[(rr * HXs + g * 4) * PITCH + cp * 2];
            if (ci < C1) {
                const float* p0 = in1 + (long long)(b * C1 + ci) * (long long)HW + (long long)y * W + xg;
                bool fast = VEC4 && (unsigned)y < (unsigned)H && xg >= 0 && (xg + 3) < W;
                if (fast) {
                    float4 a  = *(const float4*)p0;
                    float4 b2 = *(const float4*)(p0 + HW);
                    *(unsigned*)(dp)             = pack2bf(a.x, b2.x);
                    *(unsigned*)(dp + PITCH)     = pack2bf(a.y, b2.y);
                    *(unsigned*)(dp + 2 * PITCH) = pack2bf(a.z, b2.z);
                    *(unsigned*)(dp + 3 * PITCH) = pack2bf(a.w, b2.w);
                } else {
                    #pragma unroll
                    for (int u = 0; u < 4; ++u) {
                        int x = xg + u;
                        unsigned pk = 0;
                        if ((unsigned)y < (unsigned)H && (unsigned)x < (unsigned)W) {
                            pk = (unsigned)f2bf(p0[u]) | ((unsigned)f2bf(p0[u + (long long)HW]) << 16);
                        }
                        *(unsigned*)(dp + u * PITCH) = pk;
                    }
                }
            } else {
                const ushort* q0 = in2 + (long long)(b * C2 + (ci - C1)) * (long long)HW + (long long)y * W + xg;
                bool fast = VEC4 && (unsigned)y < (unsigned)H && xg >= 0 && (xg + 3) < W && (ci + 1) < Cin;
                if (fast) {
                    ushort4 a  = *(const ushort4*)q0;
                    ushort4 b2 = *(const ushort4*)(q0 + HW);
                    *(unsigned*)(dp)             = (unsigned)a.x | ((unsigned)b2.x << 16);
                    *(unsigned*)(dp + PITCH)     = (unsigned)a.y | ((unsigned)b2.y << 16);
                    *(unsigned*)(dp + 2 * PITCH) = (unsigned)a.z | ((unsigned)b2.z << 16);
                    *(unsigned*)(dp + 3 * PITCH) = (unsigned)a.w | ((unsigned)b2.w << 16);
                } else {
                    #pragma unroll
                    for (int u = 0; u < 4; ++u) {
                        int x = xg + u;
                        unsigned pk = 0;
                        if ((unsigned)y < (unsigned)H && (unsigned)x < (unsigned)W && ci < Cin) {
                            unsigned v0 = q0[u];
                            unsigned v1 = (ci + 1 < Cin) ? q0[u + (long long)HW] : 0u;
                            pk = v0 | (v1 << 16);
                        }
                        *(unsigned*)(dp + u * PITCH) = pk;
                    }
                }
            }
        }
        __syncthreads();

        bf16x8 afA[MT];
        {
            const ushort* ap = wt + (size_t)co0 * Cin_pad + ci0 + aoff;
            #pragma unroll
            for (int mt = 0; mt < MT; ++mt)
                afA[mt] = *(const bf16x8*)(ap + (size_t)mt * 16 * Cin_pad);
        }
        #pragma unroll
        for (int t = 0; t < KK; ++t) {
            bf16x8 afB[MT];
            if (t + 1 < KK) {
                const ushort* ap = wt + (size_t)((t + 1) * CoutPad + co0) * Cin_pad + ci0 + aoff;
                #pragma unroll
                for (int mt = 0; mt < MT; ++mt)
                    afB[mt] = *(const bf16x8*)(ap + (size_t)mt * 16 * Cin_pad);
            }
            const int tOff = ((t / K) * HXs + (t % K)) * PITCH;
            bf16x8 bf[NT];
            #pragma unroll
            for (int nt = 0; nt < NT; ++nt)
                bf[nt] = *(const bf16x8*)(sT + posBase[nt] + tOff);
            #pragma unroll
            for (int mt = 0; mt < MT; ++mt)
                #pragma unroll
                for (int nt = 0; nt < NT; ++nt)
                    acc[mt][nt] = __builtin_amdgcn_mfma_f32_16x16x32_bf16(
                        afA[mt], bf[nt], acc[mt][nt], 0, 0, 0);
            if (t + 1 < KK) {
                #pragma unroll
                for (int mt = 0; mt < MT; ++mt) afA[mt] = afB[mt];
            }
        }
    }

    // ---- store ----
    #pragma unroll
    for (int mt = 0; mt < MT; ++mt) {
        #pragma unroll
        for (int nt = 0; nt < NT; ++nt) {
            int y = y0 + py_[nt], x = x0 + px_[nt];
            if (y < H && x < W) {
                #pragma unroll
                for (int r = 0; r < 4; ++r) {
                    int co = co0 + mt * 16 + lg * 4 + r;
                    if (co < Cout) {
                        size_t o = ((size_t)(b * Cout + co)) * HW + (size_t)y * W + x;
                        if (OUTMODE == 0)      ((float*)outDst)[o] = acc[mt][nt][r];
                        else if (OUTMODE == 1) unsafeAtomicAdd(&((float*)outDst)[o], acc[mt][nt][r]);
                        else                   ((ushort*)outDst)[o] = f2bf(acc[mt][nt][r]);
                    }
                }
            }
        }
    }
}

// ---------------------------------------------------------------------------
// ConvTranspose2d k3/s2/p1/op1 via MFMA, 4-phase subpixel decomposition.
// bf16 packed output (phase pairs share one b32 store).
// ---------------------------------------------------------------------------
template<int TY, int TX, int NSPLIT, int MT>
__global__ __launch_bounds__(256)
void convt_mfma(const float* __restrict__ in,
                const ushort* __restrict__ wtp,
                ushort* __restrict__ out,
                int Cin, int Cout, int Cin_pad, int Hin, int Win,
                int tilesX, int tilesY) {
    constexpr int HY = TY + 1, HX = TX + 1;
    constexpr int PITCH = 40;
    constexpr int NPX = TY * TX;
    constexpr int PXW = NPX / NSPLIT;
    constexpr int NT = PXW / 16;
    constexpr int NPOS = HY * HX;
    constexpr int NIT = (NPOS * 16 + 63) & ~63;

    __shared__ ushort sT[NPOS * PITCH];

    constexpr int toy[9] = {0, 0, 0, 1, 0, 1, 1, 0, 0};
    constexpr int tox[9] = {0, 1, 0, 0, 0, 1, 0, 1, 0};
    constexpr int tph[9] = {0, 1, 1, 2, 2, 3, 3, 3, 3};

    const int tid = threadIdx.x;
    const int lane = tid & 63, wv = tid >> 6;
    const int nwave = wv % NSPLIT, mwave = wv / NSPLIT;
    const int l15 = lane & 15, lg = lane >> 4;

    int tile = blockIdx.x;
    const int txi = tile % tilesX;
    int rem = tile / tilesX;
    const int tyi = rem % tilesY;
    const int b = rem / tilesY;
    const int x0 = txi * TX, y0 = tyi * TY;
    const size_t HWi = (size_t)Hin * Win;
    const int Wo = 2 * Win;
    const size_t HWo = (size_t)4 * HWi;

    const int co0 = mwave * (MT * 16);

    int posBase[NT], py_[NT], px_[NT];
    #pragma unroll
    for (int nt = 0; nt < NT; ++nt) {
        int pidx = nwave * PXW + nt * 16 + l15;
        int py = pidx / TX, px = pidx % TX;
        py_[nt] = py; px_[nt] = px;
        posBase[nt] = (py * HX + px) * PITCH + lg * 8;
    }
    const int aoff = l15 * Cin_pad + lg * 8;

    f32x4 acc[4][MT][NT];
    #pragma unroll
    for (int p = 0; p < 4; ++p)
        #pragma unroll
        for (int i = 0; i < MT; ++i)
            #pragma unroll
            for (int j = 0; j < NT; ++j) acc[p][i][j] = (f32x4)0.f;

    const int nchunks = Cin_pad / 32;
    for (int c = 0; c < nchunks; ++c) {
        const int ci0 = c * 32;
        __syncthreads();
        for (int i = tid; i < NIT; i += 256) {
            int cp = (i >> 2) & 15;
            int pos = (i & 3) | ((i >> 6) << 2);
            if (pos < NPOS) {
                int hy = pos / HX, hx = pos % HX;
                int y = y0 + hy, x = x0 + hx;
                int ci = ci0 + cp * 2;
                unsigned pk = 0;
                if ((unsigned)y < (unsigned)Hin && (unsigned)x < (unsigned)Win && ci < Cin) {
                    const float* p0 = in + (size_t)(b * Cin + ci) * HWi + (size_t)y * Win + x;
                    float v0 = p0[0];
                    float v1 = (ci + 1 < Cin) ? p0[HWi] : 0.f;
                    pk = pack2bf(v0, v1);
                }
                *(unsigned*)&sT[pos * PITCH + cp * 2] = pk;
            }
        }
        __syncthreads();

        bf16x8 afA[MT];
        {
            const ushort* ap = wtp + (size_t)co0 * Cin_pad + ci0 + aoff;
            #pragma unroll
            for (int mt = 0; mt < MT; ++mt)
                afA[mt] = *(const bf16x8*)(ap + (size_t)mt * 16 * Cin_pad);
        }
        #pragma unroll
        for (int t = 0; t < 9; ++t) {
            bf16x8 afB[MT];
            if (t + 1 < 9) {
                const ushort* ap = wtp + (size_t)((t + 1) * Cout + co0) * Cin_pad + ci0 + aoff;
                #pragma unroll
                for (int mt = 0; mt < MT; ++mt)
                    afB[mt] = *(const bf16x8*)(ap + (size_t)mt * 16 * Cin_pad);
            }
            const int tOff = (toy[t] * HX + tox[t]) * PITCH;
            bf16x8 bf[NT];
            #pragma unroll
            for (int nt = 0; nt < NT; ++nt)
                bf[nt] = *(const bf16x8*)(sT + posBase[nt] + tOff);
            #pragma unroll
            for (int mt = 0; mt < MT; ++mt)
                #pragma unroll
                for (int nt = 0; nt < NT; ++nt)
                    acc[tph[t]][mt][nt] = __builtin_amdgcn_mfma_f32_16x16x32_bf16(
                        afA[mt], bf[nt], acc[tph[t]][mt][nt], 0, 0, 0);
            if (t + 1 < 9) {
                #pragma unroll
                for (int mt = 0; mt < MT; ++mt) afA[mt] = afB[mt];
            }
        }
    }

    #pragma unroll
    for (int dy = 0; dy < 2; ++dy) {
        #pragma unroll
        for (int mt = 0; mt < MT; ++mt) {
            #pragma unroll
            for (int nt = 0; nt < NT; ++nt) {
                int y = y0 + py_[nt], x = x0 + px_[nt];
                if (y < Hin && x < Win) {
                    #pragma unroll
                    for (int r = 0; r < 4; ++r) {
                        int co = co0 + mt * 16 + lg * 4 + r;
                        unsigned pk = pack2bf(acc[dy * 2][mt][nt][r], acc[dy * 2 + 1][mt][nt][r]);
                        *(unsigned*)&out[((size_t)(b * Cout + co)) * HWo + (size_t)(2 * y + dy) * Wo + 2 * x] = pk;
                    }
                }
            }
        }
    }
}

// ---------------------------------------------------------------------------
// InstanceNorm stats: one block per (b,c). Biased variance, eps=1e-5.
// ---------------------------------------------------------------------------
__global__ __launch_bounds__(256)
void inorm_stats(const float* __restrict__ x,
                 float* __restrict__ mean,
                 float* __restrict__ istd, int HW) {
    int bc = blockIdx.x;
    const float4* p = (const float4*)(x + (size_t)bc * HW);
    int n4 = HW >> 2;
    float s = 0.f, ss = 0.f;
    for (int i = threadIdx.x; i < n4; i += 256) {
        float4 v = p[i];
        s += v.x + v.y + v.z + v.w;
        ss += v.x * v.x + v.y * v.y + v.z * v.z + v.w * v.w;
    }
    #pragma unroll
    for (int o = 32; o > 0; o >>= 1) {
        s  += __shfl_down(s, o);
        ss += __shfl_down(ss, o);
    }
    __shared__ float sh[4][2];
    int wid = threadIdx.x >> 6, ln = threadIdx.x & 63;
    if (ln == 0) { sh[wid][0] = s; sh[wid][1] = ss; }
    __syncthreads();
    if (threadIdx.x == 0) {
        float S = 0.f, SS = 0.f;
        for (int i = 0; i < 4; ++i) { S += sh[i][0]; SS += sh[i][1]; }
        float m = S / HW;
        float v = SS / HW - m * m;
        v = v > 0.f ? v : 0.f;
        mean[bc] = m;
        istd[bc] = rsqrtf(v + 1e-5f);
    }
}

// ---------------------------------------------------------------------------
// Epilogue: feat = relu((raw - m)*istd) [+ res + br[co]]
// RESMODE: 0 none, 1 fp32 res, 2 bf16 res.
// ---------------------------------------------------------------------------
template<int RESMODE>
__global__ __launch_bounds__(256)
void epilogue_k(const float* __restrict__ raw,
                const float* __restrict__ mean,
                const float* __restrict__ istd,
                const void* __restrict__ res,
                const float* __restrict__ br,
                float* __restrict__ feat,
                int HW, int Cout, int total4) {
    int i = blockIdx.x * 256 + threadIdx.x;
    if (i >= total4) return;
    int bc = (int)(((long long)i * 4) / HW);
    float m = mean[bc], is = istd[bc];
    float4 r = ((const float4*)raw)[i];
    float4 o;
    o.x = fmaxf((r.x - m) * is, 0.f);
    o.y = fmaxf((r.y - m) * is, 0.f);
    o.z = fmaxf((r.z - m) * is, 0.f);
    o.w = fmaxf((r.w - m) * is, 0.f);
    if (RESMODE == 1) {
        float bb = br[bc % Cout];
        float4 e = ((const float4*)res)[i];
        o.x += e.x + bb; o.y += e.y + bb; o.z += e.z + bb; o.w += e.w + bb;
    } else if (RESMODE == 2) {
        float bb = br[bc % Cout];
        ushort4 e = ((const ushort4*)res)[i];
        o.x += bf2f(e.x) + bb; o.y += bf2f(e.y) + bb;
        o.z += bf2f(e.z) + bb; o.w += bf2f(e.w) + bb;
    }
    ((float4*)feat)[i] = o;
}

extern "C" void kernel_launch(void* const* d_in, const int* in_sizes, int n_in,
                              void* d_out, int out_size, void* d_ws, size_t ws_size,
                              hipStream_t stream) {
    const float* f4   = (const float*)d_in[0];
    const float* f8   = (const float*)d_in[1];
    const float* f16  = (const float*)d_in[2];
    const float* f32  = (const float*)d_in[3];
    const float* w32  = (const float*)d_in[4];
    const float* wt32 = (const float*)d_in[6];
    const float* w16  = (const float*)d_in[7];
    const float* wr16 = (const float*)d_in[9];
    const float* br16 = (const float*)d_in[10];
    const float* wt16 = (const float*)d_in[11];
    const float* w8   = (const float*)d_in[12];
    const float* wr8  = (const float*)d_in[14];
    const float* br8  = (const float*)d_in[15];
    const float* wt8  = (const float*)d_in[16];
    const float* w4   = (const float*)d_in[17];
    const float* wr4  = (const float*)d_in[19];
    const float* br4  = (const float*)d_in[20];
    // main-conv biases cancel under InstanceNorm -> unused.

    float* out = (float*)d_out;

    const int B = 2, C = 256;
    const int H4 = 160, W4 = 240;
    const int H8 = 80,  W8 = 120;
    const int H16 = 40, W16 = 60;
    const int H32 = 20, W32 = 30;

    float* feat4  = out;
    float* feat8  = out + (size_t)B * 48 * H4 * W4;
    float* feat16 = feat8 + (size_t)B * 64 * H8 * W8;
    float* feat32 = feat16 + (size_t)B * 192 * H16 * W16;

    // ws: wsUpB bf16 | wsRaw fp32 | wsResB bf16 | stats  (29.5 MB, proven)
    const size_t bufElems = (size_t)B * 48 * H4 * W4;  // 3,686,400
    ushort* wsUpB  = (ushort*)d_ws;
    float*  wsRaw  = (float*)(wsUpB + bufElems);
    ushort* wsResB = (ushort*)(wsRaw + bufElems);
    float*  stMean = (float*)(wsResB + bufElems);
    float*  stIstd = stMean + 512;

    // bf16 repacked weights live in the feat4 output region (written last).
    ushort* wb = (ushort*)feat4;
    ushort* W32p = wb;                          // 9*192*256
    ushort* W16p = W32p + 9 * 192 * 256;        // 25*192*448
    ushort* W8p  = W16p + 25 * 192 * 448;       // 25*64*320
    ushort* W4p  = W8p  + 25 * 64 * 320;        // 25*48*320
    ushort* R16p = W4p  + 25 * 48 * 320;        // 192*256
    ushort* R8p  = R16p + 192 * 256;            // 64*256
    ushort* R4p  = R8p  + 64 * 256;             // 48*256
    ushort* T32p = R4p  + 48 * 256;             // 9*192*160
    ushort* T16p = T32p + 9 * 192 * 160;        // 9*64*192
    ushort* T8p  = T16p + 9 * 64 * 192;         // 9*48*64

    // ---- weight repacks ----
    {
        int t1 = 9 * 192 * 256;
        transpose_w<<<cdiv(t1, 256), 256, 0, stream>>>(w32, W32p, 160, 192, 256, 256, 9, t1);
        int t2 = 25 * 192 * 448;
        transpose_w<<<cdiv(t2, 256), 256, 0, stream>>>(w16, W16p, 192, 192, 448, 448, 25, t2);
        int t3 = 25 * 64 * 320;
        transpose_w<<<cdiv(t3, 256), 256, 0, stream>>>(w8, W8p, 64, 64, 320, 320, 25, t3);
        int t4 = 25 * 48 * 320;
        transpose_w<<<cdiv(t4, 256), 256, 0, stream>>>(w4, W4p, 48, 48, 304, 320, 25, t4);
        int t5 = 192 * 256;
        transpose_w<<<cdiv(t5, 256), 256, 0, stream>>>(wr16, R16p, 192, 192, 256, 256, 1, t5);
        int t6 = 64 * 256;
        transpose_w<<<cdiv(t6, 256), 256, 0, stream>>>(wr8, R8p, 64, 64, 256, 256, 1, t6);
        int t7 = 48 * 256;
        transpose_w<<<cdiv(t7, 256), 256, 0, stream>>>(wr4, R4p, 48, 48, 256, 256, 1, t7);
        int u1 = 9 * 192 * 160;
        transpose_wt<<<cdiv(u1, 256), 256, 0, stream>>>(wt32, T32p, 160, 192, 160, u1);
        int u2 = 9 * 64 * 192;
        transpose_wt<<<cdiv(u2, 256), 256, 0, stream>>>(wt16, T16p, 192, 64, 192, u2);
        int u3 = 9 * 48 * 64;
        transpose_wt<<<cdiv(u3, 256), 256, 0, stream>>>(wt8, T8p, 64, 48, 64, u3);
    }

    // ---------------- stage 32 (K=3, Cin=256, Cout=160, 20x30) ----------------
    {
        hipMemsetAsync(wsRaw, 0, (size_t)B * 160 * H32 * W32 * 4, stream);
        int tX = cdiv(W32, 8), tY = cdiv(H32, 2);   // 4 x 10
        dim3 g(tX * tY, 8, B);                       // KSPLIT=8 (1 chunk each) -> 640 blocks
        conv_mfma4<3, 2, 8, 1, 4, 3, false, 1><<<g, 256, 0, stream>>>(
            f32, C, nullptr, 0, C, W32p, wsRaw,
            H32, W32, 160, 192, 256, tX, 8, 1);
        inorm_stats<<<B * 160, 256, 0, stream>>>(wsRaw, stMean, stIstd, H32 * W32);
        int tot4 = B * 160 * H32 * W32 / 4;
        epilogue_k<0><<<cdiv(tot4, 256), 256, 0, stream>>>(
            wsRaw, stMean, stIstd, nullptr, nullptr, feat32, H32 * W32, 160, tot4);
        int uX = cdiv(W32, 8), uY = cdiv(H32, 2);   // 4 x 10 -> 80 blocks
        convt_mfma<2, 8, 1, 3><<<uX * uY * B, 256, 0, stream>>>(
            feat32, T32p, wsUpB, 160, 192, 160, H32, W32, uX, uY);
    }
    // ---------------- stage 16 (K=5, Cin=256+192, Cout=192, 40x60) ------------
    {
        hipMemsetAsync(wsRaw, 0, (size_t)B * 192 * H16 * W16 * 4, stream);
        hipMemsetAsync(feat16, 0, (size_t)B * 192 * H16 * W16 * 4, stream);
        int tX = cdiv(W16, 8), tY = cdiv(H16, 4);   // 8 x 10
        dim3 g(tX * tY, 7, B);                       // KSPLIT=7 -> 1120 blocks
        conv_mfma4<5, 4, 8, 1, 4, 3, true, 1><<<g, 256, 0, stream>>>(
            f16, C, wsUpB, 192, 448, W16p, wsRaw,
            H16, W16, 192, 192, 448, tX, 14, 2);
        dim3 gr(tX * tY, 2, B);                      // KSPLIT=2 -> 320 blocks
        conv_mfma4<1, 4, 8, 1, 4, 3, true, 1><<<gr, 256, 0, stream>>>(
            f16, C, nullptr, 0, C, R16p, feat16,
            H16, W16, 192, 192, 256, tX, 8, 4);
        inorm_stats<<<B * 192, 256, 0, stream>>>(wsRaw, stMean, stIstd, H16 * W16);
        int tot4 = B * 192 * H16 * W16 / 4;
        epilogue_k<1><<<cdiv(tot4, 256), 256, 0, stream>>>(
            wsRaw, stMean, stIstd, feat16, br16, feat16, H16 * W16, 192, tot4);
        int uX = cdiv(W16, 8), uY = cdiv(H16, 2);   // 8 x 20 -> 320 blocks
        convt_mfma<2, 8, 1, 1><<<uX * uY * B, 256, 0, stream>>>(
            feat16, T16p, wsUpB, 192, 64, 192, H16, W16, uX, uY);
    }
    // ---------------- stage 8 (K=5, Cin=256+64, Cout=64, 80x120) --------------
    {
        hipMemsetAsync(wsRaw, 0, (size_t)B * 64 * H8 * W8 * 4, stream);
        hipMemsetAsync(feat8, 0, (size_t)B * 64 * H8 * W8 * 4, stream);
        int tX = cdiv(W8, 8), tY = cdiv(H8, 4);     // 15 x 20
        dim3 g(tX * tY, 5, B);                       // KSPLIT=5 -> 3000 blocks
        conv_mfma4<5, 4, 8, 2, 2, 2, true, 1><<<g, 256, 0, stream>>>(
            f8, C, wsUpB, 64, 320, W8p, wsRaw,
            H8, W8, 64, 64, 320, tX, 10, 2);
        dim3 gr(tX * tY, 2, B);                      // KSPLIT=2 -> 1200 blocks
        conv_mfma4<1, 4, 8, 2, 2, 2, true, 1><<<gr, 256, 0, stream>>>(
            f8, C, nullptr, 0, C, R8p, feat8,
            H8, W8, 64, 64, 256, tX, 8, 4);
        inorm_stats<<<B * 64, 256, 0, stream>>>(wsRaw, stMean, stIstd, H8 * W8);
        int tot4 = B * 64 * H8 * W8 / 4;
        epilogue_k<1><<<cdiv(tot4, 256), 256, 0, stream>>>(
            wsRaw, stMean, stIstd, feat8, br8, feat8, H8 * W8, 64, tot4);
        int uX = cdiv(W8, 16), uY = cdiv(H8, 4);    // 8 x 20 -> 320 blocks
        convt_mfma<4, 16, 4, 3><<<uX * uY * B, 256, 0, stream>>>(
            feat8, T8p, wsUpB, 64, 48, 64, H8, W8, uX, uY);
    }
    // ---------------- stage 4 (K=5, Cin=256+48, Cout=48, 160x240) -------------
    {
        hipMemsetAsync(wsRaw, 0, (size_t)B * 48 * H4 * W4 * 4, stream);
        int tX = cdiv(W4, 16), tY = cdiv(H4, 4);    // 15 x 40
        dim3 g(tX * tY, 2, B);                       // KSPLIT=2 -> 2400 blocks
        conv_mfma4<5, 4, 16, 4, 1, 3, true, 1><<<g, 256, 0, stream>>>(
            f4, C, wsUpB, 48, 304, W4p, wsRaw,
            H4, W4, 48, 48, 320, tX, 10, 5);
        dim3 gr(tX * tY, 1, B);                      // 1200 blocks, bf16 plain out
        conv_mfma4<1, 4, 16, 4, 1, 3, true, 2><<<gr, 256, 0, stream>>>(
            f4, C, nullptr, 0, C, R4p, wsResB,
            H4, W4, 48, 48, 256, tX, 8, 8);
        inorm_stats<<<B * 48, 256, 0, stream>>>(wsRaw, stMean, stIstd, H4 * W4);
        int tot4 = B * 48 * H4 * W4 / 4;
        epilogue_k<2><<<cdiv(tot4, 256), 256, 0, stream>>>(
            wsRaw, stMean, stIstd, wsResB, br4, feat4, H4 * W4, 48, tot4);
    }
}

// Round 8
// 873.330 us; speedup vs baseline: 1.1550x; 1.1550x over previous
//
#include <hip/hip_runtime.h>
#include <hip/hip_bf16.h>

typedef __attribute__((ext_vector_type(8))) short bf16x8;
typedef __attribute__((ext_vector_type(4))) float f32x4;

static inline int cdiv(int a, int b) { return (a + b - 1) / b; }

__device__ __forceinline__ ushort f2bf(float f) {
    unsigned u = __float_as_uint(f);
    unsigned r = (u + 0x7FFFu + ((u >> 16) & 1u)) >> 16;
    return (ushort)r;
}
__device__ __forceinline__ unsigned pack2bf(float lo, float hi) {
    unsigned r;
    asm("v_cvt_pk_bf16_f32 %0, %1, %2" : "=v"(r) : "v"(lo), "v"(hi));
    return r;
}
__device__ __forceinline__ float bf2f(ushort u) {
    return __uint_as_float((unsigned)u << 16);
}

// ---------------------------------------------------------------------------
// Weight repack: w[co][ci][t] (fp32) -> wt[t][co_pad][ci_pad] (bf16), zero-pad.
// ---------------------------------------------------------------------------
__global__ __launch_bounds__(256)
void transpose_w(const float* __restrict__ w, ushort* __restrict__ wt,
                 int Cout, int CoutPad, int Cin, int Cin_pad, int KK, int total) {
    int idx = blockIdx.x * 256 + threadIdx.x;
    if (idx >= total) return;
    int ci = idx % Cin_pad;
    int rem = idx / Cin_pad;
    int co = rem % CoutPad;
    int t  = rem / CoutPad;
    float v = (ci < Cin && co < Cout) ? w[((size_t)co * Cin + ci) * KK + t] : 0.f;
    wt[idx] = f2bf(v);
}

// ---------------------------------------------------------------------------
// ConvTranspose weight repack: torch wt[ci][co][ky][kx] -> wtp[t][co][ci_pad]
// ---------------------------------------------------------------------------
__device__ const int g_tky[9] = {1, 1, 1, 0, 2, 0, 0, 2, 2};
__device__ const int g_tkx[9] = {1, 0, 2, 1, 1, 0, 2, 0, 2};

__global__ __launch_bounds__(256)
void transpose_wt(const float* __restrict__ wt, ushort* __restrict__ dst,
                  int Cin, int Cout, int Cin_pad, int total) {
    int idx = blockIdx.x * 256 + threadIdx.x;
    if (idx >= total) return;
    int ci = idx % Cin_pad;
    int rem = idx / Cin_pad;
    int co = rem % Cout;
    int t  = rem / Cout;
    float v = 0.f;
    if (ci < Cin)
        v = wt[((size_t)(ci * Cout + co) * 3 + g_tky[t]) * 3 + g_tkx[t]];
    dst[idx] = f2bf(v);
}

// ---------------------------------------------------------------------------
// Implicit-GEMM conv via MFMA 16x16x32 bf16, v5.
//  - g-fastest staging (R5's proven coalesced global float4/ushort4 loads)
//  - rotated LDS write order per lane: c=(u+g+rr)&3. Pure issue-order
//    permutation (placement unchanged => correctness-neutral); spreads
//    per-instruction banks 32-way -> ~4-way.
//  - in1 fp32 (v_cvt_pk_bf16_f32), in2 bf16 (upsampled map).
//  - OUTMODE: 0 plain fp32, 1 atomic fp32 (split-K), 2 plain bf16.
// ---------------------------------------------------------------------------
template<int K, int TY, int TX, int NSPLIT, int MSPLIT, int MT, bool VEC4, int OUTMODE>
__global__ __launch_bounds__(256)
void conv_mfma5(const float* __restrict__ in1, int C1,
                const ushort* __restrict__ in2, int C2, int Cin,
                const ushort* __restrict__ wt,
                void* __restrict__ outDst,
                int H, int W, int Cout, int CoutPad, int Cin_pad,
                int tilesX, int nchunks, int cps) {
    constexpr int P = K / 2;
    constexpr int XOFF = (K == 1) ? 0 : 4;
    constexpr int JOFF = XOFF - P;
    constexpr int HXs = (TX + K - 1 + JOFF + 3) & ~3;
    constexpr int HY = TY + K - 1;
    constexpr int PITCH = 40;
    constexpr int KK = K * K;
    constexpr int PXW = TY * TX / NSPLIT;
    constexpr int NT = PXW / 16;
    constexpr int G = HXs / 4;
    constexpr int NITEM = 16 * HY * G;

    __shared__ ushort sT[HY * HXs * PITCH];

    const int tid = threadIdx.x;
    const int lane = tid & 63, wv = tid >> 6;
    const int nwave = wv % NSPLIT, mwave = wv / NSPLIT;
    const int l15 = lane & 15, lg = lane >> 4;

    const int txi = blockIdx.x % tilesX;
    const int tyi = blockIdx.x / tilesX;
    const int b = blockIdx.z;
    const int x0 = txi * TX, y0 = tyi * TY;
    const size_t HW = (size_t)H * W;

    const int co0 = mwave * (MT * 16);

    int posBase[NT], py_[NT], px_[NT];
    #pragma unroll
    for (int nt = 0; nt < NT; ++nt) {
        int pidx = nwave * PXW + nt * 16 + l15;
        int py = pidx / TX, px = pidx % TX;
        py_[nt] = py; px_[nt] = px;
        posBase[nt] = (py * HXs + px + JOFF) * PITCH + lg * 8;
    }
    const int aoff = l15 * Cin_pad + lg * 8;

    f32x4 acc[MT][NT];
    #pragma unroll
    for (int i = 0; i < MT; ++i)
        #pragma unroll
        for (int j = 0; j < NT; ++j) acc[i][j] = (f32x4)0.f;

    const int c0 = blockIdx.y * cps;
    const int c1 = (c0 + cps < nchunks) ? c0 + cps : nchunks;

    for (int c = c0; c < c1; ++c) {
        const int ci0 = c * 32;
        __syncthreads();
        // ---- stage halo tile: g-fastest (coalesced), rotated writes ----
        for (int i = tid; i < NITEM; i += 256) {
            int g  = i % G;
            int rr = (i / G) % HY;
            int cp = i / (G * HY);
            int ci = ci0 + cp * 2;
            int y  = y0 - P + rr;
            int xg = x0 - XOFF + g * 4;
            ushort* dp = &sT[(rr * HXs + g * 4) * PITCH + cp * 2];
            bool yok = (unsigned)y < (unsigned)H;
            unsigned dvv[4];   // static-indexed only (rule #20)
            if (ci < C1) {
                const float* p0 = in1 + (long long)(b * C1 + ci) * (long long)HW + (long long)y * W + xg;
                if (VEC4 && yok && xg >= 0 && (xg + 3) < W) {
                    float4 a  = *(const float4*)p0;
                    float4 b2 = *(const float4*)(p0 + HW);
                    dvv[0] = pack2bf(a.x, b2.x);
                    dvv[1] = pack2bf(a.y, b2.y);
                    dvv[2] = pack2bf(a.z, b2.z);
                    dvv[3] = pack2bf(a.w, b2.w);
                } else {
                    #pragma unroll
                    for (int u = 0; u < 4; ++u) {
                        int x = xg + u;
                        unsigned pk = 0;
                        if (yok && (unsigned)x < (unsigned)W)
                            pk = (unsigned)f2bf(p0[u]) | ((unsigned)f2bf(p0[u + (long long)HW]) << 16);
                        dvv[u] = pk;
                    }
                }
            } else {
                const ushort* q0 = in2 + (long long)(b * C2 + (ci - C1)) * (long long)HW + (long long)y * W + xg;
                if (VEC4 && yok && xg >= 0 && (xg + 3) < W && (ci + 1) < Cin) {
                    ushort4 a  = *(const ushort4*)q0;
                    ushort4 b2 = *(const ushort4*)(q0 + HW);
                    dvv[0] = (unsigned)a.x | ((unsigned)b2.x << 16);
                    dvv[1] = (unsigned)a.y | ((unsigned)b2.y << 16);
                    dvv[2] = (unsigned)a.z | ((unsigned)b2.z << 16);
                    dvv[3] = (unsigned)a.w | ((unsigned)b2.w << 16);
                } else {
                    #pragma unroll
                    for (int u = 0; u < 4; ++u) {
                        int x = xg + u;
                        unsigned pk = 0;
                        if (yok && (unsigned)x < (unsigned)W && ci < Cin) {
                            unsigned v0 = q0[u];
                            unsigned v1 = (ci + 1 < Cin) ? q0[u + (long long)HW] : 0u;
                            pk = v0 | (v1 << 16);
                        }
                        dvv[u] = pk;
                    }
                }
            }
            // rotated-order stores: placement unchanged, banks spread
            int s = (g + rr) & 3;
            #pragma unroll
            for (int u = 0; u < 4; ++u) {
                int cc = (u + s) & 3;
                unsigned val = (cc & 2) ? ((cc & 1) ? dvv[3] : dvv[2])
                                        : ((cc & 1) ? dvv[1] : dvv[0]);
                *(unsigned*)(dp + cc * PITCH) = val;
            }
        }
        __syncthreads();

        bf16x8 afA[MT];
        {
            const ushort* ap = wt + (size_t)co0 * Cin_pad + ci0 + aoff;
            #pragma unroll
            for (int mt = 0; mt < MT; ++mt)
                afA[mt] = *(const bf16x8*)(ap + (size_t)mt * 16 * Cin_pad);
        }
        #pragma unroll
        for (int t = 0; t < KK; ++t) {
            bf16x8 afB[MT];
            if (t + 1 < KK) {
                const ushort* ap = wt + (size_t)((t + 1) * CoutPad + co0) * Cin_pad + ci0 + aoff;
                #pragma unroll
                for (int mt = 0; mt < MT; ++mt)
                    afB[mt] = *(const bf16x8*)(ap + (size_t)mt * 16 * Cin_pad);
            }
            const int tOff = ((t / K) * HXs + (t % K)) * PITCH;
            bf16x8 bf[NT];
            #pragma unroll
            for (int nt = 0; nt < NT; ++nt)
                bf[nt] = *(const bf16x8*)(sT + posBase[nt] + tOff);
            #pragma unroll
            for (int mt = 0; mt < MT; ++mt)
                #pragma unroll
                for (int nt = 0; nt < NT; ++nt)
                    acc[mt][nt] = __builtin_amdgcn_mfma_f32_16x16x32_bf16(
                        afA[mt], bf[nt], acc[mt][nt], 0, 0, 0);
            if (t + 1 < KK) {
                #pragma unroll
                for (int mt = 0; mt < MT; ++mt) afA[mt] = afB[mt];
            }
        }
    }

    // ---- store ----
    #pragma unroll
    for (int mt = 0; mt < MT; ++mt) {
        #pragma unroll
        for (int nt = 0; nt < NT; ++nt) {
            int y = y0 + py_[nt], x = x0 + px_[nt];
            if (y < H && x < W) {
                #pragma unroll
                for (int r = 0; r < 4; ++r) {
                    int co = co0 + mt * 16 + lg * 4 + r;
                    if (co < Cout) {
                        size_t o = ((size_t)(b * Cout + co)) * HW + (size_t)y * W + x;
                        if (OUTMODE == 0)      ((float*)outDst)[o] = acc[mt][nt][r];
                        else if (OUTMODE == 1) unsafeAtomicAdd(&((float*)outDst)[o], acc[mt][nt][r]);
                        else                   ((ushort*)outDst)[o] = f2bf(acc[mt][nt][r]);
                    }
                }
            }
        }
    }
}

// ---------------------------------------------------------------------------
// ConvTranspose2d k3/s2/p1/op1 via MFMA, 4-phase subpixel decomposition.
// bf16 packed output (phase pairs share one b32 store).
// ---------------------------------------------------------------------------
template<int TY, int TX, int NSPLIT, int MT>
__global__ __launch_bounds__(256)
void convt_mfma(const float* __restrict__ in,
                const ushort* __restrict__ wtp,
                ushort* __restrict__ out,
                int Cin, int Cout, int Cin_pad, int Hin, int Win,
                int tilesX, int tilesY) {
    constexpr int HY = TY + 1, HX = TX + 1;
    constexpr int PITCH = 40;
    constexpr int NPX = TY * TX;
    constexpr int PXW = NPX / NSPLIT;
    constexpr int NT = PXW / 16;
    constexpr int NPOS = HY * HX;
    constexpr int NIT = (NPOS * 16 + 63) & ~63;

    __shared__ ushort sT[NPOS * PITCH];

    constexpr int toy[9] = {0, 0, 0, 1, 0, 1, 1, 0, 0};
    constexpr int tox[9] = {0, 1, 0, 0, 0, 1, 0, 1, 0};
    constexpr int tph[9] = {0, 1, 1, 2, 2, 3, 3, 3, 3};

    const int tid = threadIdx.x;
    const int lane = tid & 63, wv = tid >> 6;
    const int nwave = wv % NSPLIT, mwave = wv / NSPLIT;
    const int l15 = lane & 15, lg = lane >> 4;

    int tile = blockIdx.x;
    const int txi = tile % tilesX;
    int rem = tile / tilesX;
    const int tyi = rem % tilesY;
    const int b = rem / tilesY;
    const int x0 = txi * TX, y0 = tyi * TY;
    const size_t HWi = (size_t)Hin * Win;
    const int Wo = 2 * Win;
    const size_t HWo = (size_t)4 * HWi;

    const int co0 = mwave * (MT * 16);

    int posBase[NT], py_[NT], px_[NT];
    #pragma unroll
    for (int nt = 0; nt < NT; ++nt) {
        int pidx = nwave * PXW + nt * 16 + l15;
        int py = pidx / TX, px = pidx % TX;
        py_[nt] = py; px_[nt] = px;
        posBase[nt] = (py * HX + px) * PITCH + lg * 8;
    }
    const int aoff = l15 * Cin_pad + lg * 8;

    f32x4 acc[4][MT][NT];
    #pragma unroll
    for (int p = 0; p < 4; ++p)
        #pragma unroll
        for (int i = 0; i < MT; ++i)
            #pragma unroll
            for (int j = 0; j < NT; ++j) acc[p][i][j] = (f32x4)0.f;

    const int nchunks = Cin_pad / 32;
    for (int c = 0; c < nchunks; ++c) {
        const int ci0 = c * 32;
        __syncthreads();
        for (int i = tid; i < NIT; i += 256) {
            int cp = (i >> 2) & 15;
            int pos = (i & 3) | ((i >> 6) << 2);
            if (pos < NPOS) {
                int hy = pos / HX, hx = pos % HX;
                int y = y0 + hy, x = x0 + hx;
                int ci = ci0 + cp * 2;
                unsigned pk = 0;
                if ((unsigned)y < (unsigned)Hin && (unsigned)x < (unsigned)Win && ci < Cin) {
                    const float* p0 = in + (size_t)(b * Cin + ci) * HWi + (size_t)y * Win + x;
                    float v0 = p0[0];
                    float v1 = (ci + 1 < Cin) ? p0[HWi] : 0.f;
                    pk = pack2bf(v0, v1);
                }
                *(unsigned*)&sT[pos * PITCH + cp * 2] = pk;
            }
        }
        __syncthreads();

        bf16x8 afA[MT];
        {
            const ushort* ap = wtp + (size_t)co0 * Cin_pad + ci0 + aoff;
            #pragma unroll
            for (int mt = 0; mt < MT; ++mt)
                afA[mt] = *(const bf16x8*)(ap + (size_t)mt * 16 * Cin_pad);
        }
        #pragma unroll
        for (int t = 0; t < 9; ++t) {
            bf16x8 afB[MT];
            if (t + 1 < 9) {
                const ushort* ap = wtp + (size_t)((t + 1) * Cout + co0) * Cin_pad + ci0 + aoff;
                #pragma unroll
                for (int mt = 0; mt < MT; ++mt)
                    afB[mt] = *(const bf16x8*)(ap + (size_t)mt * 16 * Cin_pad);
            }
            const int tOff = (toy[t] * HX + tox[t]) * PITCH;
            bf16x8 bf[NT];
            #pragma unroll
            for (int nt = 0; nt < NT; ++nt)
                bf[nt] = *(const bf16x8*)(sT + posBase[nt] + tOff);
            #pragma unroll
            for (int mt = 0; mt < MT; ++mt)
                #pragma unroll
                for (int nt = 0; nt < NT; ++nt)
                    acc[tph[t]][mt][nt] = __builtin_amdgcn_mfma_f32_16x16x32_bf16(
                        afA[mt], bf[nt], acc[tph[t]][mt][nt], 0, 0, 0);
            if (t + 1 < 9) {
                #pragma unroll
                for (int mt = 0; mt < MT; ++mt) afA[mt] = afB[mt];
            }
        }
    }

    #pragma unroll
    for (int dy = 0; dy < 2; ++dy) {
        #pragma unroll
        for (int mt = 0; mt < MT; ++mt) {
            #pragma unroll
            for (int nt = 0; nt < NT; ++nt) {
                int y = y0 + py_[nt], x = x0 + px_[nt];
                if (y < Hin && x < Win) {
                    #pragma unroll
                    for (int r = 0; r < 4; ++r) {
                        int co = co0 + mt * 16 + lg * 4 + r;
                        unsigned pk = pack2bf(acc[dy * 2][mt][nt][r], acc[dy * 2 + 1][mt][nt][r]);
                        *(unsigned*)&out[((size_t)(b * Cout + co)) * HWo + (size_t)(2 * y + dy) * Wo + 2 * x] = pk;
                    }
                }
            }
        }
    }
}

// ---------------------------------------------------------------------------
// InstanceNorm stats: one block per (b,c). Biased variance, eps=1e-5.
// ---------------------------------------------------------------------------
__global__ __launch_bounds__(256)
void inorm_stats(const float* __restrict__ x,
                 float* __restrict__ mean,
                 float* __restrict__ istd, int HW) {
    int bc = blockIdx.x;
    const float4* p = (const float4*)(x + (size_t)bc * HW);
    int n4 = HW >> 2;
    float s = 0.f, ss = 0.f;
    for (int i = threadIdx.x; i < n4; i += 256) {
        float4 v = p[i];
        s += v.x + v.y + v.z + v.w;
        ss += v.x * v.x + v.y * v.y + v.z * v.z + v.w * v.w;
    }
    #pragma unroll
    for (int o = 32; o > 0; o >>= 1) {
        s  += __shfl_down(s, o);
        ss += __shfl_down(ss, o);
    }
    __shared__ float sh[4][2];
    int wid = threadIdx.x >> 6, ln = threadIdx.x & 63;
    if (ln == 0) { sh[wid][0] = s; sh[wid][1] = ss; }
    __syncthreads();
    if (threadIdx.x == 0) {
        float S = 0.f, SS = 0.f;
        for (int i = 0; i < 4; ++i) { S += sh[i][0]; SS += sh[i][1]; }
        float m = S / HW;
        float v = SS / HW - m * m;
        v = v > 0.f ? v : 0.f;
        mean[bc] = m;
        istd[bc] = rsqrtf(v + 1e-5f);
    }
}

// ---------------------------------------------------------------------------
// Epilogue: feat = relu((raw - m)*istd) [+ res + br[co]]
// RESMODE: 0 none, 1 fp32 res, 2 bf16 res.
// ---------------------------------------------------------------------------
template<int RESMODE>
__global__ __launch_bounds__(256)
void epilogue_k(const float* __restrict__ raw,
                const float* __restrict__ mean,
                const float* __restrict__ istd,
                const void* __restrict__ res,
                const float* __restrict__ br,
                float* __restrict__ feat,
                int HW, int Cout, int total4) {
    int i = blockIdx.x * 256 + threadIdx.x;
    if (i >= total4) return;
    int bc = (int)(((long long)i * 4) / HW);
    float m = mean[bc], is = istd[bc];
    float4 r = ((const float4*)raw)[i];
    float4 o;
    o.x = fmaxf((r.x - m) * is, 0.f);
    o.y = fmaxf((r.y - m) * is, 0.f);
    o.z = fmaxf((r.z - m) * is, 0.f);
    o.w = fmaxf((r.w - m) * is, 0.f);
    if (RESMODE == 1) {
        float bb = br[bc % Cout];
        float4 e = ((const float4*)res)[i];
        o.x += e.x + bb; o.y += e.y + bb; o.z += e.z + bb; o.w += e.w + bb;
    } else if (RESMODE == 2) {
        float bb = br[bc % Cout];
        ushort4 e = ((const ushort4*)res)[i];
        o.x += bf2f(e.x) + bb; o.y += bf2f(e.y) + bb;
        o.z += bf2f(e.z) + bb; o.w += bf2f(e.w) + bb;
    }
    ((float4*)feat)[i] = o;
}

extern "C" void kernel_launch(void* const* d_in, const int* in_sizes, int n_in,
                              void* d_out, int out_size, void* d_ws, size_t ws_size,
                              hipStream_t stream) {
    const float* f4   = (const float*)d_in[0];
    const float* f8   = (const float*)d_in[1];
    const float* f16  = (const float*)d_in[2];
    const float* f32  = (const float*)d_in[3];
    const float* w32  = (const float*)d_in[4];
    const float* wt32 = (const float*)d_in[6];
    const float* w16  = (const float*)d_in[7];
    const float* wr16 = (const float*)d_in[9];
    const float* br16 = (const float*)d_in[10];
    const float* wt16 = (const float*)d_in[11];
    const float* w8   = (const float*)d_in[12];
    const float* wr8  = (const float*)d_in[14];
    const float* br8  = (const float*)d_in[15];
    const float* wt8  = (const float*)d_in[16];
    const float* w4   = (const float*)d_in[17];
    const float* wr4  = (const float*)d_in[19];
    const float* br4  = (const float*)d_in[20];
    // main-conv biases cancel under InstanceNorm -> unused.

    float* out = (float*)d_out;

    const int B = 2, C = 256;
    const int H4 = 160, W4 = 240;
    const int H8 = 80,  W8 = 120;
    const int H16 = 40, W16 = 60;
    const int H32 = 20, W32 = 30;

    float* feat4  = out;
    float* feat8  = out + (size_t)B * 48 * H4 * W4;
    float* feat16 = feat8 + (size_t)B * 64 * H8 * W8;
    float* feat32 = feat16 + (size_t)B * 192 * H16 * W16;

    // ws: wsUpB bf16 | wsRaw fp32 | wsResB bf16 | stats  (29.5 MB, proven)
    const size_t bufElems = (size_t)B * 48 * H4 * W4;  // 3,686,400
    ushort* wsUpB  = (ushort*)d_ws;
    float*  wsRaw  = (float*)(wsUpB + bufElems);
    ushort* wsResB = (ushort*)(wsRaw + bufElems);
    float*  stMean = (float*)(wsResB + bufElems);
    float*  stIstd = stMean + 512;

    // bf16 repacked weights live in the feat4 output region (written last).
    ushort* wb = (ushort*)feat4;
    ushort* W32p = wb;                          // 9*192*256
    ushort* W16p = W32p + 9 * 192 * 256;        // 25*192*448
    ushort* W8p  = W16p + 25 * 192 * 448;       // 25*64*320
    ushort* W4p  = W8p  + 25 * 64 * 320;        // 25*48*320
    ushort* R16p = W4p  + 25 * 48 * 320;        // 192*256
    ushort* R8p  = R16p + 192 * 256;            // 64*256
    ushort* R4p  = R8p  + 64 * 256;             // 48*256
    ushort* T32p = R4p  + 48 * 256;             // 9*192*160
    ushort* T16p = T32p + 9 * 192 * 160;        // 9*64*192
    ushort* T8p  = T16p + 9 * 64 * 192;         // 9*48*64

    // ---- weight repacks ----
    {
        int t1 = 9 * 192 * 256;
        transpose_w<<<cdiv(t1, 256), 256, 0, stream>>>(w32, W32p, 160, 192, 256, 256, 9, t1);
        int t2 = 25 * 192 * 448;
        transpose_w<<<cdiv(t2, 256), 256, 0, stream>>>(w16, W16p, 192, 192, 448, 448, 25, t2);
        int t3 = 25 * 64 * 320;
        transpose_w<<<cdiv(t3, 256), 256, 0, stream>>>(w8, W8p, 64, 64, 320, 320, 25, t3);
        int t4 = 25 * 48 * 320;
        transpose_w<<<cdiv(t4, 256), 256, 0, stream>>>(w4, W4p, 48, 48, 304, 320, 25, t4);
        int t5 = 192 * 256;
        transpose_w<<<cdiv(t5, 256), 256, 0, stream>>>(wr16, R16p, 192, 192, 256, 256, 1, t5);
        int t6 = 64 * 256;
        transpose_w<<<cdiv(t6, 256), 256, 0, stream>>>(wr8, R8p, 64, 64, 256, 256, 1, t6);
        int t7 = 48 * 256;
        transpose_w<<<cdiv(t7, 256), 256, 0, stream>>>(wr4, R4p, 48, 48, 256, 256, 1, t7);
        int u1 = 9 * 192 * 160;
        transpose_wt<<<cdiv(u1, 256), 256, 0, stream>>>(wt32, T32p, 160, 192, 160, u1);
        int u2 = 9 * 64 * 192;
        transpose_wt<<<cdiv(u2, 256), 256, 0, stream>>>(wt16, T16p, 192, 64, 192, u2);
        int u3 = 9 * 48 * 64;
        transpose_wt<<<cdiv(u3, 256), 256, 0, stream>>>(wt8, T8p, 64, 48, 64, u3);
    }

    // ---------------- stage 32 (K=3, Cin=256, Cout=160, 20x30) ----------------
    {
        hipMemsetAsync(wsRaw, 0, (size_t)B * 160 * H32 * W32 * 4, stream);
        int tX = cdiv(W32, 8), tY = cdiv(H32, 4);   // 4 x 5
        dim3 g(tX * tY, 8, B);                       // KSPLIT=8 (1 chunk) -> 320 blocks
        conv_mfma5<3, 4, 8, 1, 4, 3, false, 1><<<g, 256, 0, stream>>>(
            f32, C, nullptr, 0, C, W32p, wsRaw,
            H32, W32, 160, 192, 256, tX, 8, 1);
        inorm_stats<<<B * 160, 256, 0, stream>>>(wsRaw, stMean, stIstd, H32 * W32);
        int tot4 = B * 160 * H32 * W32 / 4;
        epilogue_k<0><<<cdiv(tot4, 256), 256, 0, stream>>>(
            wsRaw, stMean, stIstd, nullptr, nullptr, feat32, H32 * W32, 160, tot4);
        int uX = cdiv(W32, 8), uY = cdiv(H32, 2);   // 80 blocks
        convt_mfma<2, 8, 1, 3><<<uX * uY * B, 256, 0, stream>>>(
            feat32, T32p, wsUpB, 160, 192, 160, H32, W32, uX, uY);
    }
    // ---------------- stage 16 (K=5, Cin=256+192, Cout=192, 40x60) ------------
    {
        hipMemsetAsync(wsRaw, 0, (size_t)B * 192 * H16 * W16 * 4, stream);
        hipMemsetAsync(feat16, 0, (size_t)B * 192 * H16 * W16 * 4, stream);
        int tX = cdiv(W16, 8), tY = cdiv(H16, 4);   // 8 x 10
        dim3 g(tX * tY, 7, B);                       // KSPLIT=7 -> 1120 blocks
        conv_mfma5<5, 4, 8, 1, 4, 3, true, 1><<<g, 256, 0, stream>>>(
            f16, C, wsUpB, 192, 448, W16p, wsRaw,
            H16, W16, 192, 192, 448, tX, 14, 2);
        dim3 gr(tX * tY, 2, B);                      // KSPLIT=2 -> 320 blocks
        conv_mfma5<1, 4, 8, 1, 4, 3, true, 1><<<gr, 256, 0, stream>>>(
            f16, C, nullptr, 0, C, R16p, feat16,
            H16, W16, 192, 192, 256, tX, 8, 4);
        inorm_stats<<<B * 192, 256, 0, stream>>>(wsRaw, stMean, stIstd, H16 * W16);
        int tot4 = B * 192 * H16 * W16 / 4;
        epilogue_k<1><<<cdiv(tot4, 256), 256, 0, stream>>>(
            wsRaw, stMean, stIstd, feat16, br16, feat16, H16 * W16, 192, tot4);
        int uX = cdiv(W16, 8), uY = cdiv(H16, 4);   // 160 blocks
        convt_mfma<4, 8, 2, 2><<<uX * uY * B, 256, 0, stream>>>(
            feat16, T16p, wsUpB, 192, 64, 192, H16, W16, uX, uY);
    }
    // ---------------- stage 8 (K=5, Cin=256+64, Cout=64, 80x120) --------------
    {
        hipMemsetAsync(wsRaw, 0, (size_t)B * 64 * H8 * W8 * 4, stream);
        hipMemsetAsync(feat8, 0, (size_t)B * 64 * H8 * W8 * 4, stream);
        int tX = cdiv(W8, 8), tY = cdiv(H8, 8);     // 15 x 10
        dim3 g(tX * tY, 5, B);                       // KSPLIT=5 -> 1500 blocks
        conv_mfma5<5, 8, 8, 2, 2, 2, true, 1><<<g, 256, 0, stream>>>(
            f8, C, wsUpB, 64, 320, W8p, wsRaw,
            H8, W8, 64, 64, 320, tX, 10, 2);
        dim3 gr(tX * tY, 2, B);                      // KSPLIT=2 -> 600 blocks
        conv_mfma5<1, 8, 8, 2, 2, 2, true, 1><<<gr, 256, 0, stream>>>(
            f8, C, nullptr, 0, C, R8p, feat8,
            H8, W8, 64, 64, 256, tX, 8, 4);
        inorm_stats<<<B * 64, 256, 0, stream>>>(wsRaw, stMean, stIstd, H8 * W8);
        int tot4 = B * 64 * H8 * W8 / 4;
        epilogue_k<1><<<cdiv(tot4, 256), 256, 0, stream>>>(
            wsRaw, stMean, stIstd, feat8, br8, feat8, H8 * W8, 64, tot4);
        int uX = cdiv(W8, 16), uY = cdiv(H8, 4);    // 320 blocks
        convt_mfma<4, 16, 4, 3><<<uX * uY * B, 256, 0, stream>>>(
            feat8, T8p, wsUpB, 64, 48, 64, H8, W8, uX, uY);
    }
    // ---------------- stage 4 (K=5, Cin=256+48, Cout=48, 160x240) -------------
    {
        hipMemsetAsync(wsRaw, 0, (size_t)B * 48 * H4 * W4 * 4, stream);
        int tX = cdiv(W4, 16), tY = cdiv(H4, 8);    // 15 x 20 = 300 tiles
        dim3 g(tX * tY, 2, B);                       // KSPLIT=2 -> 1200 blocks
        conv_mfma5<5, 8, 16, 4, 1, 3, true, 1><<<g, 256, 0, stream>>>(
            f4, C, wsUpB, 48, 304, W4p, wsRaw,
            H4, W4, 48, 48, 320, tX, 10, 5);
        dim3 gr(tX * tY, 1, B);                      // 600 blocks, bf16 plain out
        conv_mfma5<1, 8, 16, 4, 1, 3, true, 2><<<gr, 256, 0, stream>>>(
            f4, C, nullptr, 0, C, R4p, wsResB,
            H4, W4, 48, 48, 256, tX, 8, 8);
        inorm_stats<<<B * 48, 256, 0, stream>>>(wsRaw, stMean, stIstd, H4 * W4);
        int tot4 = B * 48 * H4 * W4 / 4;
        epilogue_k<2><<<cdiv(tot4, 256), 256, 0, stream>>>(
            wsRaw, stMean, stIstd, wsResB, br4, feat4, H4 * W4, 48, tot4);
    }
}

// Round 9
// 802.467 us; speedup vs baseline: 1.2569x; 1.0883x over previous
//
#include <hip/hip_runtime.h>
#include <hip/hip_bf16.h>

typedef __attribute__((ext_vector_type(8))) short bf16x8;
typedef __attribute__((ext_vector_type(4))) float f32x4;

static inline int cdiv(int a, int b) { return (a + b - 1) / b; }

__device__ __forceinline__ ushort f2bf(float f) {
    unsigned u = __float_as_uint(f);
    unsigned r = (u + 0x7FFFu + ((u >> 16) & 1u)) >> 16;
    return (ushort)r;
}
__device__ __forceinline__ unsigned pack2bf(float lo, float hi) {
    unsigned r;
    asm("v_cvt_pk_bf16_f32 %0, %1, %2" : "=v"(r) : "v"(lo), "v"(hi));
    return r;
}
__device__ __forceinline__ float bf2f(ushort u) {
    return __uint_as_float((unsigned)u << 16);
}
__device__ __forceinline__ int iclamp(int v, int lo, int hi) {
    return v < lo ? lo : (v > hi ? hi : v);
}

// ---------------------------------------------------------------------------
// Weight repack: w[co][ci][t] (fp32) -> wt[t][co_pad][ci_pad] (bf16), zero-pad.
// ---------------------------------------------------------------------------
__global__ __launch_bounds__(256)
void transpose_w(const float* __restrict__ w, ushort* __restrict__ wt,
                 int Cout, int CoutPad, int Cin, int Cin_pad, int KK, int total) {
    int idx = blockIdx.x * 256 + threadIdx.x;
    if (idx >= total) return;
    int ci = idx % Cin_pad;
    int rem = idx / Cin_pad;
    int co = rem % CoutPad;
    int t  = rem / CoutPad;
    float v = (ci < Cin && co < Cout) ? w[((size_t)co * Cin + ci) * KK + t] : 0.f;
    wt[idx] = f2bf(v);
}

// ---------------------------------------------------------------------------
// ConvTranspose weight repack: torch wt[ci][co][ky][kx] -> wtp[t][co][ci_pad]
// ---------------------------------------------------------------------------
__device__ const int g_tky[9] = {1, 1, 1, 0, 2, 0, 0, 2, 2};
__device__ const int g_tkx[9] = {1, 0, 2, 1, 1, 0, 2, 0, 2};

__global__ __launch_bounds__(256)
void transpose_wt(const float* __restrict__ wt, ushort* __restrict__ dst,
                  int Cin, int Cout, int Cin_pad, int total) {
    int idx = blockIdx.x * 256 + threadIdx.x;
    if (idx >= total) return;
    int ci = idx % Cin_pad;
    int rem = idx / Cin_pad;
    int co = rem % Cout;
    int t  = rem / Cout;
    float v = 0.f;
    if (ci < Cin)
        v = wt[((size_t)(ci * Cout + co) * 3 + g_tky[t]) * 3 + g_tkx[t]];
    dst[idx] = f2bf(v);
}

// ---------------------------------------------------------------------------
// conv_mfma6: pipelined implicit-GEMM conv (MFMA 16x16x32 bf16).
//  - T14 staging: ISSUE chunk c+1's global loads (clamped addresses, into
//    regs) before COMPUTE of chunk c; WRITE phase applies uniform window
//    masks. Requires W % 4 == 0 (all stages except 32-scale).
//  - split-K via blockIdx.y -> PARTIAL PLANES (plain stores, no atomics).
//  - XCD-bijective column-major tile swizzle (y-adjacent tiles same XCD L2).
//  - OUTMODE: 0 fp32 plane, 2 bf16 (KSPLIT==1 only).
// ---------------------------------------------------------------------------
template<int K, int TY, int TX, int NSPLIT, int MSPLIT, int MT, int OUTMODE>
__global__ __launch_bounds__(256)
void conv_mfma6(const float* __restrict__ in1, int C1,
                const ushort* __restrict__ in2, int C2, int Cin,
                const ushort* __restrict__ wt,
                void* __restrict__ outDst, size_t pStride,
                int H, int W, int Cout, int CoutPad, int Cin_pad,
                int tilesX, int tilesY, int nchunks, int cps) {
    constexpr int P = K / 2;
    constexpr int XOFF = (K == 1) ? 0 : 4;
    constexpr int JOFF = XOFF - P;
    constexpr int HXs = (TX + K - 1 + JOFF + 3) & ~3;
    constexpr int HY = TY + K - 1;
    constexpr int PITCH = 40;
    constexpr int KK = K * K;
    constexpr int PXW = TY * TX / NSPLIT;
    constexpr int NT = PXW / 16;
    constexpr int G = HXs / 4;
    constexpr int NITEM = 16 * HY * G;
    constexpr int IT = (NITEM + 255) / 256;

    __shared__ ushort sT[HY * HXs * PITCH];

    const int tid = threadIdx.x;
    const int lane = tid & 63, wv = tid >> 6;
    const int nwave = wv % NSPLIT, mwave = wv / NSPLIT;
    const int l15 = lane & 15, lg = lane >> 4;

    // XCD-bijective swizzle (m204), tiles ordered column-major (y fastest)
    const int nwg = tilesX * tilesY;
    int bid = blockIdx.x;
    int q8 = nwg >> 3, r8 = nwg & 7;
    int xcd = bid & 7, sidx = bid >> 3;
    int wg = (xcd < r8 ? xcd * (q8 + 1) : r8 * (q8 + 1) + (xcd - r8) * q8) + sidx;
    const int txi = wg / tilesY;
    const int tyi = wg % tilesY;

    const int b = blockIdx.z;
    const int x0 = txi * TX, y0 = tyi * TY;
    const size_t HW = (size_t)H * W;

    const int co0 = mwave * (MT * 16);

    int posBase[NT], py_[NT], px_[NT];
    #pragma unroll
    for (int nt = 0; nt < NT; ++nt) {
        int pidx = nwave * PXW + nt * 16 + l15;
        int py = pidx / TX, px = pidx % TX;
        py_[nt] = py; px_[nt] = px;
        posBase[nt] = (py * HXs + px + JOFF) * PITCH + lg * 8;
    }
    const int aoff = l15 * Cin_pad + lg * 8;

    f32x4 acc[MT][NT];
    #pragma unroll
    for (int i = 0; i < MT; ++i)
        #pragma unroll
        for (int j = 0; j < NT; ++j) acc[i][j] = (f32x4)0.f;

    const int c0 = blockIdx.y * cps;
    const int c1 = (c0 + cps < nchunks) ? c0 + cps : nchunks;

    uint4 rA[IT], rB[IT];

    // ---- ISSUE(c): clamped-address global loads into regs ----
    auto ISSUE = [&](int c) {
        const int ci0 = c * 32;
        const bool u1 = (ci0 < C1);
        #pragma unroll
        for (int it = 0; it < IT; ++it) {
            int i = it * 256 + tid;
            int ii = i < NITEM ? i : NITEM - 1;
            int g  = ii % G;
            int rr = (ii / G) % HY;
            int cp = ii / (G * HY);
            int ci = ci0 + cp * 2;
            int yc = iclamp(y0 - P + rr, 0, H - 1);
            int xc = iclamp(x0 - XOFF + g * 4, 0, W - 4);
            if (u1) {
                const float* p = in1 + (long long)(b * C1 + ci) * (long long)HW
                                     + (long long)yc * W + xc;
                rA[it] = *(const uint4*)p;
                rB[it] = *(const uint4*)(p + HW);
            } else {
                int cc = ci - C1; if (cc > C2 - 2) cc = C2 - 2;
                const ushort* qp = in2 + (long long)(b * C2 + cc) * (long long)HW
                                       + (long long)yc * W + xc;
                uint2 a = *(const uint2*)qp;
                uint2 bb = *(const uint2*)(qp + HW);
                rA[it].x = a.x; rA[it].y = a.y;
                rB[it].x = bb.x; rB[it].y = bb.y;
            }
        }
    };

    // ---- WRITE(c): mask + pack + rotated LDS stores ----
    auto WRITE = [&](int c) {
        const int ci0 = c * 32;
        const bool u1 = (ci0 < C1);
        #pragma unroll
        for (int it = 0; it < IT; ++it) {
            int i = it * 256 + tid;
            bool act = i < NITEM;
            int ii = act ? i : NITEM - 1;
            int g  = ii % G;
            int rr = (ii / G) % HY;
            int cp = ii / (G * HY);
            int ci = ci0 + cp * 2;
            int y  = y0 - P + rr;
            int xg = x0 - XOFF + g * 4;
            bool win = ((unsigned)y < (unsigned)H) && (xg >= 0) && (xg + 3 < W);
            bool mA, mB;
            if (u1) { mA = win; mB = win; }
            else    { mA = win && (ci < Cin); mB = win && (ci + 1 < Cin); }
            unsigned d0, d1, d2, d3;
            if (u1) {
                float4 a = *(float4*)&rA[it];
                float4 bb = *(float4*)&rB[it];
                d0 = pack2bf(mA ? a.x : 0.f, mB ? bb.x : 0.f);
                d1 = pack2bf(mA ? a.y : 0.f, mB ? bb.y : 0.f);
                d2 = pack2bf(mA ? a.z : 0.f, mB ? bb.z : 0.f);
                d3 = pack2bf(mA ? a.w : 0.f, mB ? bb.w : 0.f);
            } else {
                unsigned ax = mA ? rA[it].x : 0u, ay = mA ? rA[it].y : 0u;
                unsigned bx = mB ? rB[it].x : 0u, by = mB ? rB[it].y : 0u;
                d0 = (ax & 0xFFFFu) | (bx << 16);
                d1 = (ax >> 16) | (bx & 0xFFFF0000u);
                d2 = (ay & 0xFFFFu) | (by << 16);
                d3 = (ay >> 16) | (by & 0xFFFF0000u);
            }
            if (act) {
                ushort* dp = &sT[(rr * HXs + g * 4) * PITCH + cp * 2];
                int s = (g + rr) & 3;
                #pragma unroll
                for (int u = 0; u < 4; ++u) {
                    int cc2 = (u + s) & 3;
                    unsigned val = (cc2 & 2) ? ((cc2 & 1) ? d3 : d2)
                                             : ((cc2 & 1) ? d1 : d0);
                    *(unsigned*)(dp + cc2 * PITCH) = val;
                }
            }
        }
    };

    ISSUE(c0);
    for (int c = c0; c < c1; ++c) {
        const int ci0 = c * 32;
        __syncthreads();
        WRITE(c);
        __syncthreads();
        if (c + 1 < c1) ISSUE(c + 1);

        bf16x8 afA[MT];
        {
            const ushort* ap = wt + (size_t)co0 * Cin_pad + ci0 + aoff;
            #pragma unroll
            for (int mt = 0; mt < MT; ++mt)
                afA[mt] = *(const bf16x8*)(ap + (size_t)mt * 16 * Cin_pad);
        }
        #pragma unroll
        for (int t = 0; t < KK; ++t) {
            bf16x8 afB[MT];
            if (t + 1 < KK) {
                const ushort* ap = wt + (size_t)((t + 1) * CoutPad + co0) * Cin_pad + ci0 + aoff;
                #pragma unroll
                for (int mt = 0; mt < MT; ++mt)
                    afB[mt] = *(const bf16x8*)(ap + (size_t)mt * 16 * Cin_pad);
            }
            const int tOff = ((t / K) * HXs + (t % K)) * PITCH;
            bf16x8 bf[NT];
            #pragma unroll
            for (int nt = 0; nt < NT; ++nt)
                bf[nt] = *(const bf16x8*)(sT + posBase[nt] + tOff);
            #pragma unroll
            for (int mt = 0; mt < MT; ++mt)
                #pragma unroll
                for (int nt = 0; nt < NT; ++nt)
                    acc[mt][nt] = __builtin_amdgcn_mfma_f32_16x16x32_bf16(
                        afA[mt], bf[nt], acc[mt][nt], 0, 0, 0);
            if (t + 1 < KK) {
                #pragma unroll
                for (int mt = 0; mt < MT; ++mt) afA[mt] = afB[mt];
            }
        }
    }

    // ---- store (plain; partial plane for split-K) ----
    float* baseF = (float*)outDst + (size_t)blockIdx.y * pStride;
    #pragma unroll
    for (int mt = 0; mt < MT; ++mt) {
        #pragma unroll
        for (int nt = 0; nt < NT; ++nt) {
            int y = y0 + py_[nt], x = x0 + px_[nt];
            if (y < H && x < W) {
                #pragma unroll
                for (int r = 0; r < 4; ++r) {
                    int co = co0 + mt * 16 + lg * 4 + r;
                    if (co < Cout) {
                        size_t o = ((size_t)(b * Cout + co)) * HW + (size_t)y * W + x;
                        if (OUTMODE == 0) baseF[o] = acc[mt][nt][r];
                        else              ((ushort*)outDst)[o] = f2bf(acc[mt][nt][r]);
                    }
                }
            }
        }
    }
}

// ---------------------------------------------------------------------------
// conv_mfma5 (R8 version) — kept for stage-32 only (W=30 not %4; atomics ok,
// stage is tiny).
// ---------------------------------------------------------------------------
template<int K, int TY, int TX, int NSPLIT, int MSPLIT, int MT>
__global__ __launch_bounds__(256)
void conv_mfma5(const float* __restrict__ in1, int C1, int Cin,
                const ushort* __restrict__ wt,
                float* __restrict__ outDst,
                int H, int W, int Cout, int CoutPad, int Cin_pad,
                int tilesX, int nchunks, int cps) {
    constexpr int P = K / 2;
    constexpr int XOFF = 4;
    constexpr int JOFF = XOFF - P;
    constexpr int HXs = (TX + K - 1 + JOFF + 3) & ~3;
    constexpr int HY = TY + K - 1;
    constexpr int PITCH = 40;
    constexpr int KK = K * K;
    constexpr int PXW = TY * TX / NSPLIT;
    constexpr int NT = PXW / 16;
    constexpr int G = HXs / 4;
    constexpr int NITEM = 16 * HY * G;

    __shared__ ushort sT[HY * HXs * PITCH];

    const int tid = threadIdx.x;
    const int lane = tid & 63, wv = tid >> 6;
    const int nwave = wv % NSPLIT, mwave = wv / NSPLIT;
    const int l15 = lane & 15, lg = lane >> 4;

    const int txi = blockIdx.x % tilesX;
    const int tyi = blockIdx.x / tilesX;
    const int b = blockIdx.z;
    const int x0 = txi * TX, y0 = tyi * TY;
    const size_t HW = (size_t)H * W;
    const int co0 = mwave * (MT * 16);

    int posBase[NT], py_[NT], px_[NT];
    #pragma unroll
    for (int nt = 0; nt < NT; ++nt) {
        int pidx = nwave * PXW + nt * 16 + l15;
        int py = pidx / TX, px = pidx % TX;
        py_[nt] = py; px_[nt] = px;
        posBase[nt] = (py * HXs + px + JOFF) * PITCH + lg * 8;
    }
    const int aoff = l15 * Cin_pad + lg * 8;

    f32x4 acc[MT][NT];
    #pragma unroll
    for (int i = 0; i < MT; ++i)
        #pragma unroll
        for (int j = 0; j < NT; ++j) acc[i][j] = (f32x4)0.f;

    const int c0 = blockIdx.y * cps;
    const int c1 = (c0 + cps < nchunks) ? c0 + cps : nchunks;

    for (int c = c0; c < c1; ++c) {
        const int ci0 = c * 32;
        __syncthreads();
        for (int i = tid; i < NITEM; i += 256) {
            int g  = i % G;
            int rr = (i / G) % HY;
            int cp = i / (G * HY);
            int ci = ci0 + cp * 2;
            int y  = y0 - P + rr;
            int xg = x0 - XOFF + g * 4;
            ushort* dp = &sT[(rr * HXs + g * 4) * PITCH + cp * 2];
            const float* p0 = in1 + (long long)(b * C1 + ci) * (long long)HW + (long long)y * W + xg;
            bool yok = (unsigned)y < (unsigned)H;
            #pragma unroll
            for (int u = 0; u < 4; ++u) {
                int x = xg + u;
                unsigned pk = 0;
                if (yok && (unsigned)x < (unsigned)W)
                    pk = (unsigned)f2bf(p0[u]) | ((unsigned)f2bf(p0[u + (long long)HW]) << 16);
                *(unsigned*)(dp + u * PITCH) = pk;
            }
        }
        __syncthreads();

        bf16x8 afA[MT];
        {
            const ushort* ap = wt + (size_t)co0 * Cin_pad + ci0 + aoff;
            #pragma unroll
            for (int mt = 0; mt < MT; ++mt)
                afA[mt] = *(const bf16x8*)(ap + (size_t)mt * 16 * Cin_pad);
        }
        #pragma unroll
        for (int t = 0; t < KK; ++t) {
            bf16x8 afB[MT];
            if (t + 1 < KK) {
                const ushort* ap = wt + (size_t)((t + 1) * CoutPad + co0) * Cin_pad + ci0 + aoff;
                #pragma unroll
                for (int mt = 0; mt < MT; ++mt)
                    afB[mt] = *(const bf16x8*)(ap + (size_t)mt * 16 * Cin_pad);
            }
            const int tOff = ((t / K) * HXs + (t % K)) * PITCH;
            bf16x8 bf[NT];
            #pragma unroll
            for (int nt = 0; nt < NT; ++nt)
                bf[nt] = *(const bf16x8*)(sT + posBase[nt] + tOff);
            #pragma unroll
            for (int mt = 0; mt < MT; ++mt)
                #pragma unroll
                for (int nt = 0; nt < NT; ++nt)
                    acc[mt][nt] = __builtin_amdgcn_mfma_f32_16x16x32_bf16(
                        afA[mt], bf[nt], acc[mt][nt], 0, 0, 0);
            if (t + 1 < KK) {
                #pragma unroll
                for (int mt = 0; mt < MT; ++mt) afA[mt] = afB[mt];
            }
        }
    }

    #pragma unroll
    for (int mt = 0; mt < MT; ++mt) {
        #pragma unroll
        for (int nt = 0; nt < NT; ++nt) {
            int y = y0 + py_[nt], x = x0 + px_[nt];
            if (y < H && x < W) {
                #pragma unroll
                for (int r = 0; r < 4; ++r) {
                    int co = co0 + mt * 16 + lg * 4 + r;
                    if (co < Cout) {
                        size_t o = ((size_t)(b * Cout + co)) * HW + (size_t)y * W + x;
                        unsafeAtomicAdd(&outDst[o], acc[mt][nt][r]);
                    }
                }
            }
        }
    }
}

// ---------------------------------------------------------------------------
// ConvTranspose2d k3/s2/p1/op1 via MFMA, 4-phase subpixel decomposition.
// ---------------------------------------------------------------------------
template<int TY, int TX, int NSPLIT, int MT>
__global__ __launch_bounds__(256)
void convt_mfma(const float* __restrict__ in,
                const ushort* __restrict__ wtp,
                ushort* __restrict__ out,
                int Cin, int Cout, int Cin_pad, int Hin, int Win,
                int tilesX, int tilesY) {
    constexpr int HY = TY + 1, HX = TX + 1;
    constexpr int PITCH = 40;
    constexpr int NPX = TY * TX;
    constexpr int PXW = NPX / NSPLIT;
    constexpr int NT = PXW / 16;
    constexpr int NPOS = HY * HX;
    constexpr int NIT = (NPOS * 16 + 63) & ~63;

    __shared__ ushort sT[NPOS * PITCH];

    constexpr int toy[9] = {0, 0, 0, 1, 0, 1, 1, 0, 0};
    constexpr int tox[9] = {0, 1, 0, 0, 0, 1, 0, 1, 0};
    constexpr int tph[9] = {0, 1, 1, 2, 2, 3, 3, 3, 3};

    const int tid = threadIdx.x;
    const int lane = tid & 63, wv = tid >> 6;
    const int nwave = wv % NSPLIT, mwave = wv / NSPLIT;
    const int l15 = lane & 15, lg = lane >> 4;

    int tile = blockIdx.x;
    const int txi = tile % tilesX;
    int rem = tile / tilesX;
    const int tyi = rem % tilesY;
    const int b = rem / tilesY;
    const int x0 = txi * TX, y0 = tyi * TY;
    const size_t HWi = (size_t)Hin * Win;
    const int Wo = 2 * Win;
    const size_t HWo = (size_t)4 * HWi;

    const int co0 = mwave * (MT * 16);

    int posBase[NT], py_[NT], px_[NT];
    #pragma unroll
    for (int nt = 0; nt < NT; ++nt) {
        int pidx = nwave * PXW + nt * 16 + l15;
        int py = pidx / TX, px = pidx % TX;
        py_[nt] = py; px_[nt] = px;
        posBase[nt] = (py * HX + px) * PITCH + lg * 8;
    }
    const int aoff = l15 * Cin_pad + lg * 8;

    f32x4 acc[4][MT][NT];
    #pragma unroll
    for (int p = 0; p < 4; ++p)
        #pragma unroll
        for (int i = 0; i < MT; ++i)
            #pragma unroll
            for (int j = 0; j < NT; ++j) acc[p][i][j] = (f32x4)0.f;

    const int nchunks = Cin_pad / 32;
    for (int c = 0; c < nchunks; ++c) {
        const int ci0 = c * 32;
        __syncthreads();
        for (int i = tid; i < NIT; i += 256) {
            int cp = (i >> 2) & 15;
            int pos = (i & 3) | ((i >> 6) << 2);
            if (pos < NPOS) {
                int hy = pos / HX, hx = pos % HX;
                int y = y0 + hy, x = x0 + hx;
                int ci = ci0 + cp * 2;
                unsigned pk = 0;
                if ((unsigned)y < (unsigned)Hin && (unsigned)x < (unsigned)Win && ci < Cin) {
                    const float* p0 = in + (size_t)(b * Cin + ci) * HWi + (size_t)y * Win + x;
                    float v0 = p0[0];
                    float v1 = (ci + 1 < Cin) ? p0[HWi] : 0.f;
                    pk = pack2bf(v0, v1);
                }
                *(unsigned*)&sT[pos * PITCH + cp * 2] = pk;
            }
        }
        __syncthreads();

        bf16x8 afA[MT];
        {
            const ushort* ap = wtp + (size_t)co0 * Cin_pad + ci0 + aoff;
            #pragma unroll
            for (int mt = 0; mt < MT; ++mt)
                afA[mt] = *(const bf16x8*)(ap + (size_t)mt * 16 * Cin_pad);
        }
        #pragma unroll
        for (int t = 0; t < 9; ++t) {
            bf16x8 afB[MT];
            if (t + 1 < 9) {
                const ushort* ap = wtp + (size_t)((t + 1) * Cout + co0) * Cin_pad + ci0 + aoff;
                #pragma unroll
                for (int mt = 0; mt < MT; ++mt)
                    afB[mt] = *(const bf16x8*)(ap + (size_t)mt * 16 * Cin_pad);
            }
            const int tOff = (toy[t] * HX + tox[t]) * PITCH;
            bf16x8 bf[NT];
            #pragma unroll
            for (int nt = 0; nt < NT; ++nt)
                bf[nt] = *(const bf16x8*)(sT + posBase[nt] + tOff);
            #pragma unroll
            for (int mt = 0; mt < MT; ++mt)
                #pragma unroll
                for (int nt = 0; nt < NT; ++nt)
                    acc[tph[t]][mt][nt] = __builtin_amdgcn_mfma_f32_16x16x32_bf16(
                        afA[mt], bf[nt], acc[tph[t]][mt][nt], 0, 0, 0);
            if (t + 1 < 9) {
                #pragma unroll
                for (int mt = 0; mt < MT; ++mt) afA[mt] = afB[mt];
            }
        }
    }

    #pragma unroll
    for (int dy = 0; dy < 2; ++dy) {
        #pragma unroll
        for (int mt = 0; mt < MT; ++mt) {
            #pragma unroll
            for (int nt = 0; nt < NT; ++nt) {
                int y = y0 + py_[nt], x = x0 + px_[nt];
                if (y < Hin && x < Win) {
                    #pragma unroll
                    for (int r = 0; r < 4; ++r) {
                        int co = co0 + mt * 16 + lg * 4 + r;
                        unsigned pk = pack2bf(acc[dy * 2][mt][nt][r], acc[dy * 2 + 1][mt][nt][r]);
                        *(unsigned*)&out[((size_t)(b * Cout + co)) * HWo + (size_t)(2 * y + dy) * Wo + 2 * x] = pk;
                    }
                }
            }
        }
    }
}

// ---------------------------------------------------------------------------
// InstanceNorm stats over NS partial planes (summed per element).
// ---------------------------------------------------------------------------
__global__ __launch_bounds__(256)
void inorm_stats2(const float* __restrict__ x, size_t pStride, int NS,
                  float* __restrict__ mean, float* __restrict__ istd, int HW) {
    int bc = blockIdx.x;
    const float4* p = (const float4*)(x + (size_t)bc * HW);
    size_t st4 = pStride >> 2;
    int n4 = HW >> 2;
    float s = 0.f, ss = 0.f;
    for (int i = threadIdx.x; i < n4; i += 256) {
        float4 v = p[i];
        for (int sp = 1; sp < NS; ++sp) {
            float4 w = p[i + sp * st4];
            v.x += w.x; v.y += w.y; v.z += w.z; v.w += w.w;
        }
        s += v.x + v.y + v.z + v.w;
        ss += v.x * v.x + v.y * v.y + v.z * v.z + v.w * v.w;
    }
    #pragma unroll
    for (int o = 32; o > 0; o >>= 1) {
        s  += __shfl_down(s, o);
        ss += __shfl_down(ss, o);
    }
    __shared__ float sh[4][2];
    int wid = threadIdx.x >> 6, ln = threadIdx.x & 63;
    if (ln == 0) { sh[wid][0] = s; sh[wid][1] = ss; }
    __syncthreads();
    if (threadIdx.x == 0) {
        float S = 0.f, SS = 0.f;
        for (int i = 0; i < 4; ++i) { S += sh[i][0]; SS += sh[i][1]; }
        float m = S / HW;
        float v = SS / HW - m * m;
        v = v > 0.f ? v : 0.f;
        mean[bc] = m;
        istd[bc] = rsqrtf(v + 1e-5f);
    }
}

// ---------------------------------------------------------------------------
// Epilogue over partial planes: feat = relu((Σraw - m)*istd) [+ Σres + br]
// RESMODE: 0 none, 1 fp32 res planes, 2 bf16 res single plane.
// ---------------------------------------------------------------------------
template<int RESMODE>
__global__ __launch_bounds__(256)
void epilogue2(const float* __restrict__ raw, size_t rawStride, int NS,
               const float* __restrict__ mean,
               const float* __restrict__ istd,
               const void* __restrict__ res, size_t resStride, int NSR,
               const float* __restrict__ br,
               float* __restrict__ feat,
               int HW, int Cout, int total4) {
    int i = blockIdx.x * 256 + threadIdx.x;
    if (i >= total4) return;
    int bc = (int)(((long long)i * 4) / HW);
    float m = mean[bc], is = istd[bc];
    size_t rs4 = rawStride >> 2;
    float4 r = ((const float4*)raw)[i];
    for (int sp = 1; sp < NS; ++sp) {
        float4 w = ((const float4*)raw)[i + sp * rs4];
        r.x += w.x; r.y += w.y; r.z += w.z; r.w += w.w;
    }
    float4 o;
    o.x = fmaxf((r.x - m) * is, 0.f);
    o.y = fmaxf((r.y - m) * is, 0.f);
    o.z = fmaxf((r.z - m) * is, 0.f);
    o.w = fmaxf((r.w - m) * is, 0.f);
    if (RESMODE == 1) {
        float bb = br[bc % Cout];
        size_t es4 = resStride >> 2;
        float4 e = ((const float4*)res)[i];
        for (int sp = 1; sp < NSR; ++sp) {
            float4 w = ((const float4*)res)[i + sp * es4];
            e.x += w.x; e.y += w.y; e.z += w.z; e.w += w.w;
        }
        o.x += e.x + bb; o.y += e.y + bb; o.z += e.z + bb; o.w += e.w + bb;
    } else if (RESMODE == 2) {
        float bb = br[bc % Cout];
        ushort4 e = ((const ushort4*)res)[i];
        o.x += bf2f(e.x) + bb; o.y += bf2f(e.y) + bb;
        o.z += bf2f(e.z) + bb; o.w += bf2f(e.w) + bb;
    }
    ((float4*)feat)[i] = o;
}

extern "C" void kernel_launch(void* const* d_in, const int* in_sizes, int n_in,
                              void* d_out, int out_size, void* d_ws, size_t ws_size,
                              hipStream_t stream) {
    const float* f4   = (const float*)d_in[0];
    const float* f8   = (const float*)d_in[1];
    const float* f16  = (const float*)d_in[2];
    const float* f32  = (const float*)d_in[3];
    const float* w32  = (const float*)d_in[4];
    const float* wt32 = (const float*)d_in[6];
    const float* w16  = (const float*)d_in[7];
    const float* wr16 = (const float*)d_in[9];
    const float* br16 = (const float*)d_in[10];
    const float* wt16 = (const float*)d_in[11];
    const float* w8   = (const float*)d_in[12];
    const float* wr8  = (const float*)d_in[14];
    const float* br8  = (const float*)d_in[15];
    const float* wt8  = (const float*)d_in[16];
    const float* w4   = (const float*)d_in[17];
    const float* wr4  = (const float*)d_in[19];
    const float* br4  = (const float*)d_in[20];
    // main-conv biases cancel under InstanceNorm -> unused.

    float* out = (float*)d_out;

    const int B = 2, C = 256;
    const int H4 = 160, W4 = 240;
    const int H8 = 80,  W8 = 120;
    const int H16 = 40, W16 = 60;
    const int H32 = 20, W32 = 30;

    float* feat4  = out;
    float* feat8  = out + (size_t)B * 48 * H4 * W4;
    float* feat16 = feat8 + (size_t)B * 64 * H8 * W8;
    float* feat32 = feat16 + (size_t)B * 192 * H16 * W16;

    // ws: wsUpB bf16 (7.4MB) | wsRawP fp32 partials (14.7MB) | wsResP (7.4MB) | stats
    const size_t bufElems = (size_t)B * 48 * H4 * W4;  // 3,686,400
    ushort* wsUpB  = (ushort*)d_ws;
    float*  wsRawP = (float*)(wsUpB + bufElems);
    ushort* wsResB = (ushort*)(wsRawP + bufElems);     // also fp32 res partials
    float*  stMean = (float*)(wsResB + bufElems);
    float*  stIstd = stMean + 512;
    float*  wsResF = (float*)wsResB;

    // bf16 repacked weights in the feat4 output region (written last).
    ushort* wb = (ushort*)feat4;
    ushort* W32p = wb;
    ushort* W16p = W32p + 9 * 192 * 256;
    ushort* W8p  = W16p + 25 * 192 * 448;
    ushort* W4p  = W8p  + 25 * 64 * 320;
    ushort* R16p = W4p  + 25 * 48 * 320;
    ushort* R8p  = R16p + 192 * 256;
    ushort* R4p  = R8p  + 64 * 256;
    ushort* T32p = R4p  + 48 * 256;
    ushort* T16p = T32p + 9 * 192 * 160;
    ushort* T8p  = T16p + 9 * 64 * 192;

    // ---- weight repacks ----
    {
        int t1 = 9 * 192 * 256;
        transpose_w<<<cdiv(t1, 256), 256, 0, stream>>>(w32, W32p, 160, 192, 256, 256, 9, t1);
        int t2 = 25 * 192 * 448;
        transpose_w<<<cdiv(t2, 256), 256, 0, stream>>>(w16, W16p, 192, 192, 448, 448, 25, t2);
        int t3 = 25 * 64 * 320;
        transpose_w<<<cdiv(t3, 256), 256, 0, stream>>>(w8, W8p, 64, 64, 320, 320, 25, t3);
        int t4 = 25 * 48 * 320;
        transpose_w<<<cdiv(t4, 256), 256, 0, stream>>>(w4, W4p, 48, 48, 304, 320, 25, t4);
        int t5 = 192 * 256;
        transpose_w<<<cdiv(t5, 256), 256, 0, stream>>>(wr16, R16p, 192, 192, 256, 256, 1, t5);
        int t6 = 64 * 256;
        transpose_w<<<cdiv(t6, 256), 256, 0, stream>>>(wr8, R8p, 64, 64, 256, 256, 1, t6);
        int t7 = 48 * 256;
        transpose_w<<<cdiv(t7, 256), 256, 0, stream>>>(wr4, R4p, 48, 48, 256, 256, 1, t7);
        int u1 = 9 * 192 * 160;
        transpose_wt<<<cdiv(u1, 256), 256, 0, stream>>>(wt32, T32p, 160, 192, 160, u1);
        int u2 = 9 * 64 * 192;
        transpose_wt<<<cdiv(u2, 256), 256, 0, stream>>>(wt16, T16p, 192, 64, 192, u2);
        int u3 = 9 * 48 * 64;
        transpose_wt<<<cdiv(u3, 256), 256, 0, stream>>>(wt8, T8p, 64, 48, 64, u3);
    }

    // ---------------- stage 32 (K=3, Cin=256, Cout=160, 20x30) ----------------
    {
        hipMemsetAsync(wsRawP, 0, (size_t)B * 160 * H32 * W32 * 4, stream);
        int tX = cdiv(W32, 8), tY = cdiv(H32, 4);   // 4 x 5
        dim3 g(tX * tY, 8, B);                       // atomic split-K (tiny stage)
        conv_mfma5<3, 4, 8, 1, 4, 3><<<g, 256, 0, stream>>>(
            f32, C, C, W32p, wsRawP, H32, W32, 160, 192, 256, tX, 8, 1);
        inorm_stats2<<<B * 160, 256, 0, stream>>>(wsRawP, 0, 1, stMean, stIstd, H32 * W32);
        int tot4 = B * 160 * H32 * W32 / 4;
        epilogue2<0><<<cdiv(tot4, 256), 256, 0, stream>>>(
            wsRawP, 0, 1, stMean, stIstd, nullptr, 0, 0, nullptr, feat32, H32 * W32, 160, tot4);
        int uX = cdiv(W32, 8), uY = cdiv(H32, 2);
        convt_mfma<2, 8, 1, 3><<<uX * uY * B, 256, 0, stream>>>(
            feat32, T32p, wsUpB, 160, 192, 160, H32, W32, uX, uY);
    }
    // ---------------- stage 16 (K=5, Cin=256+192, Cout=192, 40x60) ------------
    {
        size_t SZ16 = (size_t)B * 192 * H16 * W16;  // 921,600
        int tX = cdiv(W16, 8), tY = cdiv(H16, 4);   // 8 x 10
        dim3 g(tX * tY, 3, B);                       // KSPLIT=3 partial planes
        conv_mfma6<5, 4, 8, 1, 4, 3, 0><<<g, 256, 0, stream>>>(
            f16, C, wsUpB, 192, 448, W16p, wsRawP, SZ16,
            H16, W16, 192, 192, 448, tX, tY, 14, 5);
        dim3 gr(tX * tY, 2, B);                      // res KSPLIT=2 partial planes
        conv_mfma6<1, 4, 8, 1, 4, 3, 0><<<gr, 256, 0, stream>>>(
            f16, C, nullptr, 0, C, R16p, wsResF, SZ16,
            H16, W16, 192, 192, 256, tX, tY, 8, 4);
        inorm_stats2<<<B * 192, 256, 0, stream>>>(wsRawP, SZ16, 3, stMean, stIstd, H16 * W16);
        int tot4 = (int)(SZ16 / 4);
        epilogue2<1><<<cdiv(tot4, 256), 256, 0, stream>>>(
            wsRawP, SZ16, 3, stMean, stIstd, wsResF, SZ16, 2, br16, feat16, H16 * W16, 192, tot4);
        int uX = cdiv(W16, 8), uY = cdiv(H16, 4);
        convt_mfma<4, 8, 2, 2><<<uX * uY * B, 256, 0, stream>>>(
            feat16, T16p, wsUpB, 192, 64, 192, H16, W16, uX, uY);
    }
    // ---------------- stage 8 (K=5, Cin=256+64, Cout=64, 80x120) --------------
    {
        size_t SZ8 = (size_t)B * 64 * H8 * W8;      // 1,228,800
        int tX = cdiv(W8, 16), tY = cdiv(H8, 8);    // 8 x 10
        dim3 g(tX * tY, 3, B);                       // KSPLIT=3 partial planes
        conv_mfma6<5, 8, 16, 2, 2, 2, 0><<<g, 256, 0, stream>>>(
            f8, C, wsUpB, 64, 320, W8p, wsRawP, SZ8,
            H8, W8, 64, 64, 320, tX, tY, 10, 4);
        dim3 gr(tX * tY, 1, B);                      // res KSPLIT=1
        conv_mfma6<1, 8, 16, 2, 2, 2, 0><<<gr, 256, 0, stream>>>(
            f8, C, nullptr, 0, C, R8p, wsResF, SZ8,
            H8, W8, 64, 64, 256, tX, tY, 8, 8);
        inorm_stats2<<<B * 64, 256, 0, stream>>>(wsRawP, SZ8, 3, stMean, stIstd, H8 * W8);
        int tot4 = (int)(SZ8 / 4);
        epilogue2<1><<<cdiv(tot4, 256), 256, 0, stream>>>(
            wsRawP, SZ8, 3, stMean, stIstd, wsResF, SZ8, 1, br8, feat8, H8 * W8, 64, tot4);
        int uX = cdiv(W8, 16), uY = cdiv(H8, 4);
        convt_mfma<4, 16, 4, 3><<<uX * uY * B, 256, 0, stream>>>(
            feat8, T8p, wsUpB, 64, 48, 64, H8, W8, uX, uY);
    }
    // ---------------- stage 4 (K=5, Cin=256+48, Cout=48, 160x240) -------------
    {
        size_t SZ4 = (size_t)B * 48 * H4 * W4;      // 3,686,400
        int tX = cdiv(W4, 16), tY = cdiv(H4, 8);    // 15 x 20 = 300 tiles
        dim3 g(tX * tY, 1, B);                       // KSPLIT=1, 600 blocks
        conv_mfma6<5, 8, 16, 4, 1, 3, 0><<<g, 256, 0, stream>>>(
            f4, C, wsUpB, 48, 304, W4p, wsRawP, SZ4,
            H4, W4, 48, 48, 320, tX, tY, 10, 10);
        conv_mfma6<1, 8, 16, 4, 1, 3, 2><<<g, 256, 0, stream>>>(
            f4, C, nullptr, 0, C, R4p, wsResB, 0,
            H4, W4, 48, 48, 256, tX, tY, 8, 8);
        inorm_stats2<<<B * 48, 256, 0, stream>>>(wsRawP, 0, 1, stMean, stIstd, H4 * W4);
        int tot4 = (int)(SZ4 / 4);
        epilogue2<2><<<cdiv(tot4, 256), 256, 0, stream>>>(
            wsRawP, 0, 1, stMean, stIstd, wsResB, 0, 0, br4, feat4, H4 * W4, 48, tot4);
    }
}

// Round 10
// 594.144 us; speedup vs baseline: 1.6977x; 1.3506x over previous
//
#include <hip/hip_runtime.h>
#include <hip/hip_bf16.h>

typedef __attribute__((ext_vector_type(8))) short bf16x8;
typedef __attribute__((ext_vector_type(4))) float f32x4;

static inline int cdiv(int a, int b) { return (a + b - 1) / b; }

__device__ __forceinline__ ushort f2bf(float f) {
    unsigned u = __float_as_uint(f);
    unsigned r = (u + 0x7FFFu + ((u >> 16) & 1u)) >> 16;
    return (ushort)r;
}
__device__ __forceinline__ unsigned pack2bf(float lo, float hi) {
    unsigned r;
    asm("v_cvt_pk_bf16_f32 %0, %1, %2" : "=v"(r) : "v"(lo), "v"(hi));
    return r;
}
__device__ __forceinline__ float bf2f(ushort u) {
    return __uint_as_float((unsigned)u << 16);
}

// ---------------------------------------------------------------------------
// Weight repack: w[co][ci][t] (fp32) -> wt[t][co_pad][ci_pad] (bf16), zero-pad.
// ---------------------------------------------------------------------------
__global__ __launch_bounds__(256)
void transpose_w(const float* __restrict__ w, ushort* __restrict__ wt,
                 int Cout, int CoutPad, int Cin, int Cin_pad, int KK, int total) {
    int idx = blockIdx.x * 256 + threadIdx.x;
    if (idx >= total) return;
    int ci = idx % Cin_pad;
    int rem = idx / Cin_pad;
    int co = rem % CoutPad;
    int t  = rem / CoutPad;
    float v = (ci < Cin && co < Cout) ? w[((size_t)co * Cin + ci) * KK + t] : 0.f;
    wt[idx] = f2bf(v);
}

// ---------------------------------------------------------------------------
// ConvTranspose weight repack: torch wt[ci][co][ky][kx] -> wtp[t][co][ci_pad]
// ---------------------------------------------------------------------------
__device__ const int g_tky[9] = {1, 1, 1, 0, 2, 0, 0, 2, 2};
__device__ const int g_tkx[9] = {1, 0, 2, 1, 1, 0, 2, 0, 2};

__global__ __launch_bounds__(256)
void transpose_wt(const float* __restrict__ wt, ushort* __restrict__ dst,
                  int Cin, int Cout, int Cin_pad, int total) {
    int idx = blockIdx.x * 256 + threadIdx.x;
    if (idx >= total) return;
    int ci = idx % Cin_pad;
    int rem = idx / Cin_pad;
    int co = rem % Cout;
    int t  = rem / Cout;
    float v = 0.f;
    if (ci < Cin)
        v = wt[((size_t)(ci * Cout + co) * 3 + g_tky[t]) * 3 + g_tkx[t]];
    dst[idx] = f2bf(v);
}

// ---------------------------------------------------------------------------
// conv_mfma7: implicit-GEMM conv, MFMA 16x16x32 bf16.
//  - direct staging (g-fastest coalesced, rotated LDS writes ~4-way banks)
//  - DEPTH-4 weight A-frag pipeline: af[4], preload 3 taps, load tap t+3
//    BEFORE tap t's MFMAs (slot (t+3)&3 != t&3; static idx under unroll).
//  - NT=4: per tap 4 ds_read_b128 + MT*4 MFMAs -> tap work covers L2 latency.
//  - XCD-bijective tile swizzle; split-K -> partial planes (no atomics).
//  - OUTMODE: 0 fp32 plane, 2 bf16 (KSPLIT==1 only).
// ---------------------------------------------------------------------------
template<int K, int TY, int TX, int NSPLIT, int MSPLIT, int MT, int OUTMODE>
__global__ __launch_bounds__(256)
void conv_mfma7(const float* __restrict__ in1, int C1,
                const ushort* __restrict__ in2, int C2, int Cin,
                const ushort* __restrict__ wt,
                void* __restrict__ outDst, size_t pStride,
                int H, int W, int Cout, int CoutPad, int Cin_pad,
                int tilesX, int tilesY, int nchunks, int cps) {
    constexpr int P = K / 2;
    constexpr int XOFF = (K == 1) ? 0 : 4;
    constexpr int JOFF = XOFF - P;
    constexpr int HXs = (TX + K - 1 + JOFF + 3) & ~3;
    constexpr int HY = TY + K - 1;
    constexpr int PITCH = 40;
    constexpr int KK = K * K;
    constexpr int PXW = TY * TX / NSPLIT;
    constexpr int NT = PXW / 16;
    constexpr int G = HXs / 4;
    constexpr int NITEM = 16 * HY * G;

    __shared__ ushort sT[HY * HXs * PITCH];

    const int tid = threadIdx.x;
    const int lane = tid & 63, wv = tid >> 6;
    const int nwave = wv % NSPLIT, mwave = wv / NSPLIT;
    const int l15 = lane & 15, lg = lane >> 4;

    // XCD-bijective swizzle (m204), tiles column-major (y fastest)
    const int nwg = tilesX * tilesY;
    int bid = blockIdx.x;
    int q8 = nwg >> 3, r8 = nwg & 7;
    int xcd = bid & 7, sidx = bid >> 3;
    int wg = (xcd < r8 ? xcd * (q8 + 1) : r8 * (q8 + 1) + (xcd - r8) * q8) + sidx;
    const int txi = wg / tilesY;
    const int tyi = wg % tilesY;

    const int b = blockIdx.z;
    const int x0 = txi * TX, y0 = tyi * TY;
    const size_t HW = (size_t)H * W;

    const int co0 = mwave * (MT * 16);

    int posBase[NT], py_[NT], px_[NT];
    #pragma unroll
    for (int nt = 0; nt < NT; ++nt) {
        int pidx = nwave * PXW + nt * 16 + l15;
        int py = pidx / TX, px = pidx % TX;
        py_[nt] = py; px_[nt] = px;
        posBase[nt] = (py * HXs + px + JOFF) * PITCH + lg * 8;
    }
    const int aoff = l15 * Cin_pad + lg * 8;

    f32x4 acc[MT][NT];
    #pragma unroll
    for (int i = 0; i < MT; ++i)
        #pragma unroll
        for (int j = 0; j < NT; ++j) acc[i][j] = (f32x4)0.f;

    const int c0 = blockIdx.y * cps;
    const int c1 = (c0 + cps < nchunks) ? c0 + cps : nchunks;

    for (int c = c0; c < c1; ++c) {
        const int ci0 = c * 32;
        __syncthreads();
        // ---- stage halo tile: g-fastest (coalesced), rotated LDS writes ----
        for (int i = tid; i < NITEM; i += 256) {
            int g  = i % G;
            int rr = (i / G) % HY;
            int cp = i / (G * HY);
            int ci = ci0 + cp * 2;
            int y  = y0 - P + rr;
            int xg = x0 - XOFF + g * 4;
            ushort* dp = &sT[(rr * HXs + g * 4) * PITCH + cp * 2];
            bool yok = (unsigned)y < (unsigned)H;
            unsigned d0, d1, d2, d3;
            if (ci < C1) {
                const float* p0 = in1 + (long long)(b * C1 + ci) * (long long)HW + (long long)y * W + xg;
                if (yok && xg >= 0 && (xg + 3) < W) {
                    float4 a  = *(const float4*)p0;
                    float4 b2 = *(const float4*)(p0 + HW);
                    d0 = pack2bf(a.x, b2.x);
                    d1 = pack2bf(a.y, b2.y);
                    d2 = pack2bf(a.z, b2.z);
                    d3 = pack2bf(a.w, b2.w);
                } else {
                    unsigned t0 = 0, t1 = 0, t2 = 0, t3 = 0;
                    #pragma unroll
                    for (int u = 0; u < 4; ++u) {
                        int x = xg + u;
                        unsigned pk = 0;
                        if (yok && (unsigned)x < (unsigned)W)
                            pk = (unsigned)f2bf(p0[u]) | ((unsigned)f2bf(p0[u + (long long)HW]) << 16);
                        if (u == 0) t0 = pk; else if (u == 1) t1 = pk;
                        else if (u == 2) t2 = pk; else t3 = pk;
                    }
                    d0 = t0; d1 = t1; d2 = t2; d3 = t3;
                }
            } else {
                const ushort* q0 = in2 + (long long)(b * C2 + (ci - C1)) * (long long)HW + (long long)y * W + xg;
                if (yok && xg >= 0 && (xg + 3) < W && (ci + 1) < Cin) {
                    ushort4 a  = *(const ushort4*)q0;
                    ushort4 b2 = *(const ushort4*)(q0 + HW);
                    d0 = (unsigned)a.x | ((unsigned)b2.x << 16);
                    d1 = (unsigned)a.y | ((unsigned)b2.y << 16);
                    d2 = (unsigned)a.z | ((unsigned)b2.z << 16);
                    d3 = (unsigned)a.w | ((unsigned)b2.w << 16);
                } else {
                    unsigned t0 = 0, t1 = 0, t2 = 0, t3 = 0;
                    #pragma unroll
                    for (int u = 0; u < 4; ++u) {
                        int x = xg + u;
                        unsigned pk = 0;
                        if (yok && (unsigned)x < (unsigned)W && ci < Cin) {
                            unsigned v0 = q0[u];
                            unsigned v1 = (ci + 1 < Cin) ? q0[u + (long long)HW] : 0u;
                            pk = v0 | (v1 << 16);
                        }
                        if (u == 0) t0 = pk; else if (u == 1) t1 = pk;
                        else if (u == 2) t2 = pk; else t3 = pk;
                    }
                    d0 = t0; d1 = t1; d2 = t2; d3 = t3;
                }
            }
            int s = (g + rr) & 3;
            #pragma unroll
            for (int u = 0; u < 4; ++u) {
                int cc2 = (u + s) & 3;
                unsigned val = (cc2 & 2) ? ((cc2 & 1) ? d3 : d2)
                                         : ((cc2 & 1) ? d1 : d0);
                *(unsigned*)(dp + cc2 * PITCH) = val;
            }
        }
        __syncthreads();

        // ---- depth-4 weight pipeline ----
        bf16x8 af[4][MT];
        #pragma unroll
        for (int s = 0; s < 3; ++s) {
            if (s < KK) {
                const ushort* ap = wt + (size_t)((size_t)s * CoutPad + co0) * Cin_pad + ci0 + aoff;
                #pragma unroll
                for (int mt = 0; mt < MT; ++mt)
                    af[s][mt] = *(const bf16x8*)(ap + (size_t)mt * 16 * Cin_pad);
            }
        }
        #pragma unroll
        for (int t = 0; t < KK; ++t) {
            if (t + 3 < KK) {
                const ushort* ap = wt + (size_t)((size_t)(t + 3) * CoutPad + co0) * Cin_pad + ci0 + aoff;
                #pragma unroll
                for (int mt = 0; mt < MT; ++mt)
                    af[(t + 3) & 3][mt] = *(const bf16x8*)(ap + (size_t)mt * 16 * Cin_pad);
            }
            const int tOff = ((t / K) * HXs + (t % K)) * PITCH;
            bf16x8 bf[NT];
            #pragma unroll
            for (int nt = 0; nt < NT; ++nt)
                bf[nt] = *(const bf16x8*)(sT + posBase[nt] + tOff);
            #pragma unroll
            for (int mt = 0; mt < MT; ++mt)
                #pragma unroll
                for (int nt = 0; nt < NT; ++nt)
                    acc[mt][nt] = __builtin_amdgcn_mfma_f32_16x16x32_bf16(
                        af[t & 3][mt], bf[nt], acc[mt][nt], 0, 0, 0);
        }
    }

    // ---- store (plain; partial plane for split-K) ----
    float* baseF = (float*)outDst + (size_t)blockIdx.y * pStride;
    #pragma unroll
    for (int mt = 0; mt < MT; ++mt) {
        #pragma unroll
        for (int nt = 0; nt < NT; ++nt) {
            int y = y0 + py_[nt], x = x0 + px_[nt];
            if (y < H && x < W) {
                #pragma unroll
                for (int r = 0; r < 4; ++r) {
                    int co = co0 + mt * 16 + lg * 4 + r;
                    if (co < Cout) {
                        size_t o = ((size_t)(b * Cout + co)) * HW + (size_t)y * W + x;
                        if (OUTMODE == 0) baseF[o] = acc[mt][nt][r];
                        else              ((ushort*)outDst)[o] = f2bf(acc[mt][nt][r]);
                    }
                }
            }
        }
    }
}

// ---------------------------------------------------------------------------
// conv_mfma5 — stage-32 only (W=30 not %4; tiny stage, atomics fine).
// ---------------------------------------------------------------------------
template<int K, int TY, int TX, int NSPLIT, int MSPLIT, int MT>
__global__ __launch_bounds__(256)
void conv_mfma5(const float* __restrict__ in1, int C1, int Cin,
                const ushort* __restrict__ wt,
                float* __restrict__ outDst,
                int H, int W, int Cout, int CoutPad, int Cin_pad,
                int tilesX, int nchunks, int cps) {
    constexpr int P = K / 2;
    constexpr int XOFF = 4;
    constexpr int JOFF = XOFF - P;
    constexpr int HXs = (TX + K - 1 + JOFF + 3) & ~3;
    constexpr int HY = TY + K - 1;
    constexpr int PITCH = 40;
    constexpr int KK = K * K;
    constexpr int PXW = TY * TX / NSPLIT;
    constexpr int NT = PXW / 16;
    constexpr int G = HXs / 4;
    constexpr int NITEM = 16 * HY * G;

    __shared__ ushort sT[HY * HXs * PITCH];

    const int tid = threadIdx.x;
    const int lane = tid & 63, wv = tid >> 6;
    const int nwave = wv % NSPLIT, mwave = wv / NSPLIT;
    const int l15 = lane & 15, lg = lane >> 4;

    const int txi = blockIdx.x % tilesX;
    const int tyi = blockIdx.x / tilesX;
    const int b = blockIdx.z;
    const int x0 = txi * TX, y0 = tyi * TY;
    const size_t HW = (size_t)H * W;
    const int co0 = mwave * (MT * 16);

    int posBase[NT], py_[NT], px_[NT];
    #pragma unroll
    for (int nt = 0; nt < NT; ++nt) {
        int pidx = nwave * PXW + nt * 16 + l15;
        int py = pidx / TX, px = pidx % TX;
        py_[nt] = py; px_[nt] = px;
        posBase[nt] = (py * HXs + px + JOFF) * PITCH + lg * 8;
    }
    const int aoff = l15 * Cin_pad + lg * 8;

    f32x4 acc[MT][NT];
    #pragma unroll
    for (int i = 0; i < MT; ++i)
        #pragma unroll
        for (int j = 0; j < NT; ++j) acc[i][j] = (f32x4)0.f;

    const int c0 = blockIdx.y * cps;
    const int c1 = (c0 + cps < nchunks) ? c0 + cps : nchunks;

    for (int c = c0; c < c1; ++c) {
        const int ci0 = c * 32;
        __syncthreads();
        for (int i = tid; i < NITEM; i += 256) {
            int g  = i % G;
            int rr = (i / G) % HY;
            int cp = i / (G * HY);
            int ci = ci0 + cp * 2;
            int y  = y0 - P + rr;
            int xg = x0 - XOFF + g * 4;
            ushort* dp = &sT[(rr * HXs + g * 4) * PITCH + cp * 2];
            const float* p0 = in1 + (long long)(b * C1 + ci) * (long long)HW + (long long)y * W + xg;
            bool yok = (unsigned)y < (unsigned)H;
            #pragma unroll
            for (int u = 0; u < 4; ++u) {
                int x = xg + u;
                unsigned pk = 0;
                if (yok && (unsigned)x < (unsigned)W)
                    pk = (unsigned)f2bf(p0[u]) | ((unsigned)f2bf(p0[u + (long long)HW]) << 16);
                *(unsigned*)(dp + u * PITCH) = pk;
            }
        }
        __syncthreads();

        bf16x8 afA[MT];
        {
            const ushort* ap = wt + (size_t)co0 * Cin_pad + ci0 + aoff;
            #pragma unroll
            for (int mt = 0; mt < MT; ++mt)
                afA[mt] = *(const bf16x8*)(ap + (size_t)mt * 16 * Cin_pad);
        }
        #pragma unroll
        for (int t = 0; t < KK; ++t) {
            bf16x8 afB[MT];
            if (t + 1 < KK) {
                const ushort* ap = wt + (size_t)((t + 1) * CoutPad + co0) * Cin_pad + ci0 + aoff;
                #pragma unroll
                for (int mt = 0; mt < MT; ++mt)
                    afB[mt] = *(const bf16x8*)(ap + (size_t)mt * 16 * Cin_pad);
            }
            const int tOff = ((t / K) * HXs + (t % K)) * PITCH;
            bf16x8 bf[NT];
            #pragma unroll
            for (int nt = 0; nt < NT; ++nt)
                bf[nt] = *(const bf16x8*)(sT + posBase[nt] + tOff);
            #pragma unroll
            for (int mt = 0; mt < MT; ++mt)
                #pragma unroll
                for (int nt = 0; nt < NT; ++nt)
                    acc[mt][nt] = __builtin_amdgcn_mfma_f32_16x16x32_bf16(
                        afA[mt], bf[nt], acc[mt][nt], 0, 0, 0);
            if (t + 1 < KK) {
                #pragma unroll
                for (int mt = 0; mt < MT; ++mt) afA[mt] = afB[mt];
            }
        }
    }

    #pragma unroll
    for (int mt = 0; mt < MT; ++mt) {
        #pragma unroll
        for (int nt = 0; nt < NT; ++nt) {
            int y = y0 + py_[nt], x = x0 + px_[nt];
            if (y < H && x < W) {
                #pragma unroll
                for (int r = 0; r < 4; ++r) {
                    int co = co0 + mt * 16 + lg * 4 + r;
                    if (co < Cout) {
                        size_t o = ((size_t)(b * Cout + co)) * HW + (size_t)y * W + x;
                        unsafeAtomicAdd(&outDst[o], acc[mt][nt][r]);
                    }
                }
            }
        }
    }
}

// ---------------------------------------------------------------------------
// ConvTranspose2d k3/s2/p1/op1 via MFMA, 4-phase subpixel decomposition.
// ---------------------------------------------------------------------------
template<int TY, int TX, int NSPLIT, int MT>
__global__ __launch_bounds__(256)
void convt_mfma(const float* __restrict__ in,
                const ushort* __restrict__ wtp,
                ushort* __restrict__ out,
                int Cin, int Cout, int Cin_pad, int Hin, int Win,
                int tilesX, int tilesY) {
    constexpr int HY = TY + 1, HX = TX + 1;
    constexpr int PITCH = 40;
    constexpr int NPX = TY * TX;
    constexpr int PXW = NPX / NSPLIT;
    constexpr int NT = PXW / 16;
    constexpr int NPOS = HY * HX;
    constexpr int NIT = (NPOS * 16 + 63) & ~63;

    __shared__ ushort sT[NPOS * PITCH];

    constexpr int toy[9] = {0, 0, 0, 1, 0, 1, 1, 0, 0};
    constexpr int tox[9] = {0, 1, 0, 0, 0, 1, 0, 1, 0};
    constexpr int tph[9] = {0, 1, 1, 2, 2, 3, 3, 3, 3};

    const int tid = threadIdx.x;
    const int lane = tid & 63, wv = tid >> 6;
    const int nwave = wv % NSPLIT, mwave = wv / NSPLIT;
    const int l15 = lane & 15, lg = lane >> 4;

    int tile = blockIdx.x;
    const int txi = tile % tilesX;
    int rem = tile / tilesX;
    const int tyi = rem % tilesY;
    const int b = rem / tilesY;
    const int x0 = txi * TX, y0 = tyi * TY;
    const size_t HWi = (size_t)Hin * Win;
    const int Wo = 2 * Win;
    const size_t HWo = (size_t)4 * HWi;

    const int co0 = mwave * (MT * 16);

    int posBase[NT], py_[NT], px_[NT];
    #pragma unroll
    for (int nt = 0; nt < NT; ++nt) {
        int pidx = nwave * PXW + nt * 16 + l15;
        int py = pidx / TX, px = pidx % TX;
        py_[nt] = py; px_[nt] = px;
        posBase[nt] = (py * HX + px) * PITCH + lg * 8;
    }
    const int aoff = l15 * Cin_pad + lg * 8;

    f32x4 acc[4][MT][NT];
    #pragma unroll
    for (int p = 0; p < 4; ++p)
        #pragma unroll
        for (int i = 0; i < MT; ++i)
            #pragma unroll
            for (int j = 0; j < NT; ++j) acc[p][i][j] = (f32x4)0.f;

    const int nchunks = Cin_pad / 32;
    for (int c = 0; c < nchunks; ++c) {
        const int ci0 = c * 32;
        __syncthreads();
        for (int i = tid; i < NIT; i += 256) {
            int cp = (i >> 2) & 15;
            int pos = (i & 3) | ((i >> 6) << 2);
            if (pos < NPOS) {
                int hy = pos / HX, hx = pos % HX;
                int y = y0 + hy, x = x0 + hx;
                int ci = ci0 + cp * 2;
                unsigned pk = 0;
                if ((unsigned)y < (unsigned)Hin && (unsigned)x < (unsigned)Win && ci < Cin) {
                    const float* p0 = in + (size_t)(b * Cin + ci) * HWi + (size_t)y * Win + x;
                    float v0 = p0[0];
                    float v1 = (ci + 1 < Cin) ? p0[HWi] : 0.f;
                    pk = pack2bf(v0, v1);
                }
                *(unsigned*)&sT[pos * PITCH + cp * 2] = pk;
            }
        }
        __syncthreads();

        bf16x8 afA[MT];
        {
            const ushort* ap = wtp + (size_t)co0 * Cin_pad + ci0 + aoff;
            #pragma unroll
            for (int mt = 0; mt < MT; ++mt)
                afA[mt] = *(const bf16x8*)(ap + (size_t)mt * 16 * Cin_pad);
        }
        #pragma unroll
        for (int t = 0; t < 9; ++t) {
            bf16x8 afB[MT];
            if (t + 1 < 9) {
                const ushort* ap = wtp + (size_t)((t + 1) * Cout + co0) * Cin_pad + ci0 + aoff;
                #pragma unroll
                for (int mt = 0; mt < MT; ++mt)
                    afB[mt] = *(const bf16x8*)(ap + (size_t)mt * 16 * Cin_pad);
            }
            const int tOff = (toy[t] * HX + tox[t]) * PITCH;
            bf16x8 bf[NT];
            #pragma unroll
            for (int nt = 0; nt < NT; ++nt)
                bf[nt] = *(const bf16x8*)(sT + posBase[nt] + tOff);
            #pragma unroll
            for (int mt = 0; mt < MT; ++mt)
                #pragma unroll
                for (int nt = 0; nt < NT; ++nt)
                    acc[tph[t]][mt][nt] = __builtin_amdgcn_mfma_f32_16x16x32_bf16(
                        afA[mt], bf[nt], acc[tph[t]][mt][nt], 0, 0, 0);
            if (t + 1 < 9) {
                #pragma unroll
                for (int mt = 0; mt < MT; ++mt) afA[mt] = afB[mt];
            }
        }
    }

    #pragma unroll
    for (int dy = 0; dy < 2; ++dy) {
        #pragma unroll
        for (int mt = 0; mt < MT; ++mt) {
            #pragma unroll
            for (int nt = 0; nt < NT; ++nt) {
                int y = y0 + py_[nt], x = x0 + px_[nt];
                if (y < Hin && x < Win) {
                    #pragma unroll
                    for (int r = 0; r < 4; ++r) {
                        int co = co0 + mt * 16 + lg * 4 + r;
                        unsigned pk = pack2bf(acc[dy * 2][mt][nt][r], acc[dy * 2 + 1][mt][nt][r]);
                        *(unsigned*)&out[((size_t)(b * Cout + co)) * HWo + (size_t)(2 * y + dy) * Wo + 2 * x] = pk;
                    }
                }
            }
        }
    }
}

// ---------------------------------------------------------------------------
// InstanceNorm stats over NS partial planes (summed per element).
// ---------------------------------------------------------------------------
__global__ __launch_bounds__(256)
void inorm_stats2(const float* __restrict__ x, size_t pStride, int NS,
                  float* __restrict__ mean, float* __restrict__ istd, int HW) {
    int bc = blockIdx.x;
    const float4* p = (const float4*)(x + (size_t)bc * HW);
    size_t st4 = pStride >> 2;
    int n4 = HW >> 2;
    float s = 0.f, ss = 0.f;
    for (int i = threadIdx.x; i < n4; i += 256) {
        float4 v = p[i];
        for (int sp = 1; sp < NS; ++sp) {
            float4 w = p[i + sp * st4];
            v.x += w.x; v.y += w.y; v.z += w.z; v.w += w.w;
        }
        s += v.x + v.y + v.z + v.w;
        ss += v.x * v.x + v.y * v.y + v.z * v.z + v.w * v.w;
    }
    #pragma unroll
    for (int o = 32; o > 0; o >>= 1) {
        s  += __shfl_down(s, o);
        ss += __shfl_down(ss, o);
    }
    __shared__ float sh[4][2];
    int wid = threadIdx.x >> 6, ln = threadIdx.x & 63;
    if (ln == 0) { sh[wid][0] = s; sh[wid][1] = ss; }
    __syncthreads();
    if (threadIdx.x == 0) {
        float S = 0.f, SS = 0.f;
        for (int i = 0; i < 4; ++i) { S += sh[i][0]; SS += sh[i][1]; }
        float m = S / HW;
        float v = SS / HW - m * m;
        v = v > 0.f ? v : 0.f;
        mean[bc] = m;
        istd[bc] = rsqrtf(v + 1e-5f);
    }
}

// ---------------------------------------------------------------------------
// Epilogue over partial planes: feat = relu((Σraw - m)*istd) [+ Σres + br]
// RESMODE: 0 none, 1 fp32 res planes, 2 bf16 res single plane.
// ---------------------------------------------------------------------------
template<int RESMODE>
__global__ __launch_bounds__(256)
void epilogue2(const float* __restrict__ raw, size_t rawStride, int NS,
               const float* __restrict__ mean,
               const float* __restrict__ istd,
               const void* __restrict__ res, size_t resStride, int NSR,
               const float* __restrict__ br,
               float* __restrict__ feat,
               int HW, int Cout, int total4) {
    int i = blockIdx.x * 256 + threadIdx.x;
    if (i >= total4) return;
    int bc = (int)(((long long)i * 4) / HW);
    float m = mean[bc], is = istd[bc];
    size_t rs4 = rawStride >> 2;
    float4 r = ((const float4*)raw)[i];
    for (int sp = 1; sp < NS; ++sp) {
        float4 w = ((const float4*)raw)[i + sp * rs4];
        r.x += w.x; r.y += w.y; r.z += w.z; r.w += w.w;
    }
    float4 o;
    o.x = fmaxf((r.x - m) * is, 0.f);
    o.y = fmaxf((r.y - m) * is, 0.f);
    o.z = fmaxf((r.z - m) * is, 0.f);
    o.w = fmaxf((r.w - m) * is, 0.f);
    if (RESMODE == 1) {
        float bb = br[bc % Cout];
        size_t es4 = resStride >> 2;
        float4 e = ((const float4*)res)[i];
        for (int sp = 1; sp < NSR; ++sp) {
            float4 w = ((const float4*)res)[i + sp * es4];
            e.x += w.x; e.y += w.y; e.z += w.z; e.w += w.w;
        }
        o.x += e.x + bb; o.y += e.y + bb; o.z += e.z + bb; o.w += e.w + bb;
    } else if (RESMODE == 2) {
        float bb = br[bc % Cout];
        ushort4 e = ((const ushort4*)res)[i];
        o.x += bf2f(e.x) + bb; o.y += bf2f(e.y) + bb;
        o.z += bf2f(e.z) + bb; o.w += bf2f(e.w) + bb;
    }
    ((float4*)feat)[i] = o;
}

extern "C" void kernel_launch(void* const* d_in, const int* in_sizes, int n_in,
                              void* d_out, int out_size, void* d_ws, size_t ws_size,
                              hipStream_t stream) {
    const float* f4   = (const float*)d_in[0];
    const float* f8   = (const float*)d_in[1];
    const float* f16  = (const float*)d_in[2];
    const float* f32  = (const float*)d_in[3];
    const float* w32  = (const float*)d_in[4];
    const float* wt32 = (const float*)d_in[6];
    const float* w16  = (const float*)d_in[7];
    const float* wr16 = (const float*)d_in[9];
    const float* br16 = (const float*)d_in[10];
    const float* wt16 = (const float*)d_in[11];
    const float* w8   = (const float*)d_in[12];
    const float* wr8  = (const float*)d_in[14];
    const float* br8  = (const float*)d_in[15];
    const float* wt8  = (const float*)d_in[16];
    const float* w4   = (const float*)d_in[17];
    const float* wr4  = (const float*)d_in[19];
    const float* br4  = (const float*)d_in[20];
    // main-conv biases cancel under InstanceNorm -> unused.

    float* out = (float*)d_out;

    const int B = 2, C = 256;
    const int H4 = 160, W4 = 240;
    const int H8 = 80,  W8 = 120;
    const int H16 = 40, W16 = 60;
    const int H32 = 20, W32 = 30;

    float* feat4  = out;
    float* feat8  = out + (size_t)B * 48 * H4 * W4;
    float* feat16 = feat8 + (size_t)B * 64 * H8 * W8;
    float* feat32 = feat16 + (size_t)B * 192 * H16 * W16;

    // ws: wsUpB bf16 (7.4MB) | wsRawP fp32 partial planes (14.7MB) |
    //     wsResB bf16 / wsResF fp32 partials (7.4MB) | stats
    const size_t bufElems = (size_t)B * 48 * H4 * W4;  // 3,686,400
    ushort* wsUpB  = (ushort*)d_ws;
    float*  wsRawP = (float*)(wsUpB + bufElems);
    ushort* wsResB = (ushort*)(wsRawP + bufElems);
    float*  stMean = (float*)(wsResB + bufElems);
    float*  stIstd = stMean + 512;
    float*  wsResF = (float*)wsResB;

    // bf16 repacked weights in the feat4 output region (written last).
    ushort* wb = (ushort*)feat4;
    ushort* W32p = wb;                          // 9*192*256
    ushort* W16p = W32p + 9 * 192 * 256;        // 25*192*448
    ushort* W8p  = W16p + 25 * 192 * 448;       // 25*64*320
    ushort* W4p  = W8p  + 25 * 64 * 320;        // 25*64*320 (Cout pad 48->64)
    ushort* R16p = W4p  + 25 * 64 * 320;        // 192*256
    ushort* R8p  = R16p + 192 * 256;            // 64*256
    ushort* R4p  = R8p  + 64 * 256;             // 64*256 (pad)
    ushort* T32p = R4p  + 64 * 256;             // 9*192*160
    ushort* T16p = T32p + 9 * 192 * 160;        // 9*64*192
    ushort* T8p  = T16p + 9 * 64 * 192;         // 9*48*64
    // total ~4.1M ushorts = 8.2MB < feat4's 14.7MB.

    // ---- weight repacks ----
    {
        int t1 = 9 * 192 * 256;
        transpose_w<<<cdiv(t1, 256), 256, 0, stream>>>(w32, W32p, 160, 192, 256, 256, 9, t1);
        int t2 = 25 * 192 * 448;
        transpose_w<<<cdiv(t2, 256), 256, 0, stream>>>(w16, W16p, 192, 192, 448, 448, 25, t2);
        int t3 = 25 * 64 * 320;
        transpose_w<<<cdiv(t3, 256), 256, 0, stream>>>(w8, W8p, 64, 64, 320, 320, 25, t3);
        int t4 = 25 * 64 * 320;
        transpose_w<<<cdiv(t4, 256), 256, 0, stream>>>(w4, W4p, 48, 64, 304, 320, 25, t4);
        int t5 = 192 * 256;
        transpose_w<<<cdiv(t5, 256), 256, 0, stream>>>(wr16, R16p, 192, 192, 256, 256, 1, t5);
        int t6 = 64 * 256;
        transpose_w<<<cdiv(t6, 256), 256, 0, stream>>>(wr8, R8p, 64, 64, 256, 256, 1, t6);
        int t7 = 64 * 256;
        transpose_w<<<cdiv(t7, 256), 256, 0, stream>>>(wr4, R4p, 48, 64, 256, 256, 1, t7);
        int u1 = 9 * 192 * 160;
        transpose_wt<<<cdiv(u1, 256), 256, 0, stream>>>(wt32, T32p, 160, 192, 160, u1);
        int u2 = 9 * 64 * 192;
        transpose_wt<<<cdiv(u2, 256), 256, 0, stream>>>(wt16, T16p, 192, 64, 192, u2);
        int u3 = 9 * 48 * 64;
        transpose_wt<<<cdiv(u3, 256), 256, 0, stream>>>(wt8, T8p, 64, 48, 64, u3);
    }

    // ---------------- stage 32 (K=3, Cin=256, Cout=160, 20x30) ----------------
    {
        hipMemsetAsync(wsRawP, 0, (size_t)B * 160 * H32 * W32 * 4, stream);
        int tX = cdiv(W32, 8), tY = cdiv(H32, 4);   // 4 x 5
        dim3 g(tX * tY, 8, B);
        conv_mfma5<3, 4, 8, 1, 4, 3><<<g, 256, 0, stream>>>(
            f32, C, C, W32p, wsRawP, H32, W32, 160, 192, 256, tX, 8, 1);
        inorm_stats2<<<B * 160, 256, 0, stream>>>(wsRawP, 0, 1, stMean, stIstd, H32 * W32);
        int tot4 = B * 160 * H32 * W32 / 4;
        epilogue2<0><<<cdiv(tot4, 256), 256, 0, stream>>>(
            wsRawP, 0, 1, stMean, stIstd, nullptr, 0, 0, nullptr, feat32, H32 * W32, 160, tot4);
        int uX = cdiv(W32, 8), uY = cdiv(H32, 2);
        convt_mfma<2, 8, 1, 3><<<uX * uY * B, 256, 0, stream>>>(
            feat32, T32p, wsUpB, 160, 192, 160, H32, W32, uX, uY);
    }
    // ---------------- stage 16 (K=5, Cin=256+192, Cout=192, 40x60) ------------
    {
        size_t SZ16 = (size_t)B * 192 * H16 * W16;  // 921,600
        int tX = cdiv(W16, 8), tY = cdiv(H16, 8);   // 8 x 5
        dim3 g(tX * tY, 4, B);                       // KSPLIT=4 planes (4,4,4,2)
        conv_mfma7<5, 8, 8, 1, 4, 3, 0><<<g, 256, 0, stream>>>(
            f16, C, wsUpB, 192, 448, W16p, wsRawP, SZ16,
            H16, W16, 192, 192, 448, tX, tY, 14, 4);
        dim3 gr(tX * tY, 2, B);                      // res KSPLIT=2 planes
        conv_mfma7<1, 8, 8, 1, 4, 3, 0><<<gr, 256, 0, stream>>>(
            f16, C, nullptr, 0, C, R16p, wsResF, SZ16,
            H16, W16, 192, 192, 256, tX, tY, 8, 4);
        inorm_stats2<<<B * 192, 256, 0, stream>>>(wsRawP, SZ16, 4, stMean, stIstd, H16 * W16);
        int tot4 = (int)(SZ16 / 4);
        epilogue2<1><<<cdiv(tot4, 256), 256, 0, stream>>>(
            wsRawP, SZ16, 4, stMean, stIstd, wsResF, SZ16, 2, br16, feat16, H16 * W16, 192, tot4);
        int uX = cdiv(W16, 8), uY = cdiv(H16, 4);
        convt_mfma<4, 8, 2, 2><<<uX * uY * B, 256, 0, stream>>>(
            feat16, T16p, wsUpB, 192, 64, 192, H16, W16, uX, uY);
    }
    // ---------------- stage 8 (K=5, Cin=256+64, Cout=64, 80x120) --------------
    {
        size_t SZ8 = (size_t)B * 64 * H8 * W8;      // 1,228,800
        int tX = cdiv(W8, 16), tY = cdiv(H8, 8);    // 8 x 10
        dim3 g(tX * tY, 3, B);                       // KSPLIT=3 planes (4,4,2)
        conv_mfma7<5, 8, 16, 2, 2, 2, 0><<<g, 256, 0, stream>>>(
            f8, C, wsUpB, 64, 320, W8p, wsRawP, SZ8,
            H8, W8, 64, 64, 320, tX, tY, 10, 4);
        dim3 gr(tX * cdiv(H8, 4), 1, B);             // res: TY=4 -> 160 tiles
        conv_mfma7<1, 4, 16, 1, 4, 1, 0><<<gr, 256, 0, stream>>>(
            f8, C, nullptr, 0, C, R8p, wsResF, SZ8,
            H8, W8, 64, 64, 256, tX, cdiv(H8, 4), 8, 8);
        inorm_stats2<<<B * 64, 256, 0, stream>>>(wsRawP, SZ8, 3, stMean, stIstd, H8 * W8);
        int tot4 = (int)(SZ8 / 4);
        epilogue2<1><<<cdiv(tot4, 256), 256, 0, stream>>>(
            wsRawP, SZ8, 3, stMean, stIstd, wsResF, SZ8, 1, br8, feat8, H8 * W8, 64, tot4);
        int uX = cdiv(W8, 16), uY = cdiv(H8, 4);
        convt_mfma<4, 16, 4, 3><<<uX * uY * B, 256, 0, stream>>>(
            feat8, T8p, wsUpB, 64, 48, 64, H8, W8, uX, uY);
    }
    // ---------------- stage 4 (K=5, Cin=256+48, Cout=48->64pad, 160x240) ------
    {
        size_t SZ4 = (size_t)B * 48 * H4 * W4;      // 3,686,400
        int tX = cdiv(W4, 16), tY = cdiv(H4, 8);    // 15 x 20 = 300 tiles
        dim3 g(tX * tY, 1, B);                       // KSPLIT=1 -> 600 blocks
        conv_mfma7<5, 8, 16, 2, 2, 2, 0><<<g, 256, 0, stream>>>(
            f4, C, wsUpB, 48, 304, W4p, wsRawP, SZ4,
            H4, W4, 48, 64, 320, tX, tY, 10, 10);
        conv_mfma7<1, 8, 16, 2, 2, 2, 2><<<g, 256, 0, stream>>>(
            f4, C, nullptr, 0, C, R4p, wsResB, 0,
            H4, W4, 48, 64, 256, tX, tY, 8, 8);
        inorm_stats2<<<B * 48, 256, 0, stream>>>(wsRawP, 0, 1, stMean, stIstd, H4 * W4);
        int tot4 = (int)(SZ4 / 4);
        epilogue2<2><<<cdiv(tot4, 256), 256, 0, stream>>>(
            wsRawP, 0, 1, stMean, stIstd, wsResB, 0, 0, br4, feat4, H4 * W4, 48, tot4);
    }
}